// Round 2
// baseline (122857.861 us; speedup 1.0000x reference)
//
#include <hip/hip_runtime.h>
#include <hip/hip_bf16.h>
#include <hip/hip_fp16.h>
#include <math.h>

#define BB 64
#define CDIM 512
#define TT 1024
#define TP 512
#define HID 256
#define NEMB 30
#define GDIM 768
#define XP 271
#define HP 128

typedef _Float16 v2h __attribute__((ext_vector_type(2)));

struct TanhC { float c[7]; };

__device__ inline float f_dot2(v2h a, v2h b, float c) {
#if __has_builtin(__builtin_amdgcn_fdot2)
  return __builtin_amdgcn_fdot2(a, b, c, false);
#else
  return c + (float)a.x * (float)b.x + (float)a.y * (float)b.y;
#endif
}

__device__ inline v2h u2v(unsigned u) { return __builtin_bit_cast(v2h, u); }
__device__ inline unsigned v2u(v2h h) { return __builtin_bit_cast(unsigned, h); }
__device__ inline v2h h2v(__half2 h) { return __builtin_bit_cast(v2h, h); }
__device__ inline v2h v2splat(float f) {
  _Float16 h = (_Float16)f;
  v2h r = {h, h};
  return r;
}

// input loader: isb=1 -> bf16, else f32
__device__ inline float ldin(const void* p, long i, int isb) {
  if (isb) {
    unsigned u = ((const unsigned short*)p)[i];
    return __uint_as_float(u << 16);
  }
  return ((const float*)p)[i];
}

template <int CTRL, int RM, int BM, bool BC>
__device__ inline float dpp_add(float v) {
  int m = __builtin_amdgcn_update_dpp(0, __builtin_bit_cast(int, v), CTRL, RM, BM, BC);
  return v + __builtin_bit_cast(float, m);
}
// full wave64 sum; result valid in lane 63
__device__ inline float wave_sum64(float v) {
  v = dpp_add<0x111, 0xf, 0xf, true>(v);
  v = dpp_add<0x112, 0xf, 0xf, true>(v);
  v = dpp_add<0x114, 0xf, 0xe, false>(v);
  v = dpp_add<0x118, 0xf, 0xc, false>(v);
  v = dpp_add<0x142, 0xa, 0xf, false>(v);
  v = dpp_add<0x143, 0xc, 0xf, false>(v);
  return v;
}

// ---------------- dtype sniffer ----------------
__global__ void k_sniff(const void* fea, int* flag) {
  __shared__ int s[256];
  int tid = threadIdx.x;
  const unsigned short* u16 = (const unsigned short*)fea;
  int cnt = 0;
  for (int i = tid; i < 2048; i += 256) {
    unsigned u = u16[2 * i];
    float v = __uint_as_float(u << 16);
    float a = fabsf(v);
    if (a > 1e-6f && a < 16.0f) cnt++;
  }
  s[tid] = cnt;
  __syncthreads();
  for (int off = 128; off > 0; off >>= 1) {
    if (tid < off) s[tid] += s[tid + off];
    __syncthreads();
  }
  if (tid == 0) flag[0] = (s[0] > 1024) ? 1 : 0;
}

// ---------------- converters ----------------
__global__ void k_cvt_h(const void* src, __half* dst, long n, const int* flag) {
  int isb = flag[0];
  long i = (long)blockIdx.x * blockDim.x + threadIdx.x;
  long stride = (long)gridDim.x * blockDim.x;
  for (; i < n; i += stride) dst[i] = __float2half(ldin(src, i, isb));
}

__global__ void k_cvt_f(const void* src, float* dst, long n, const int* flag) {
  int isb = flag[0];
  long i = (long)blockIdx.x * blockDim.x + threadIdx.x;
  long stride = (long)gridDim.x * blockDim.x;
  for (; i < n; i += stride) dst[i] = ldin(src, i, isb);
}

// pack row pairs: dst[cp*cols + j] = (src[2cp][j], src[2cp+1][j])
__global__ void k_pair(const void* src, __half2* dst, int pairs, int cols, const int* flag) {
  int isb = flag[0];
  long n = (long)pairs * cols;
  long i = (long)blockIdx.x * blockDim.x + threadIdx.x;
  long stride = (long)gridDim.x * blockDim.x;
  for (; i < n; i += stride) {
    long cp = i / cols, j = i % cols;
    dst[i] = __floats2half2_rn(ldin(src, (2 * cp) * (long)cols + j, isb),
                               ldin(src, (2 * cp + 1) * (long)cols + j, isb));
  }
}

// combined output head: comb_w[k][o] (o<30 struct via sg1@sg2, o in 30..33 loc via lg1@lg2)
__global__ void k_comb(const void* sg1w, const void* sg1b, const void* sg2w, const void* sg2b,
                       const void* lg1w, const void* lg1b, const void* lg2w, const void* lg2b,
                       float* comb_w, float* comb_b, const int* flag) {
  int isb = flag[0];
  int tid = threadIdx.x;  // 256 threads, 1 block; tid = k (row)
  float acc[34];
#pragma unroll
  for (int o = 0; o < 34; ++o) acc[o] = 0.f;
  for (int m = 0; m < HID; ++m) {
    float s1 = ldin(sg1w, (long)tid * HID + m, isb);
    float l1 = ldin(lg1w, (long)tid * HID + m, isb);
#pragma unroll
    for (int o = 0; o < 30; ++o) acc[o] += s1 * ldin(sg2w, (long)m * NEMB + o, isb);
#pragma unroll
    for (int o = 0; o < 4; ++o) acc[30 + o] += l1 * ldin(lg2w, (long)m * 4 + o, isb);
  }
  for (int o = 0; o < 34; ++o) comb_w[tid * 34 + o] = acc[o];
  if (tid < 34) {
    float a = 0.f;
    if (tid < 30) {
      for (int m = 0; m < HID; ++m) a += ldin(sg1b, m, isb) * ldin(sg2w, (long)m * NEMB + tid, isb);
      a += ldin(sg2b, tid, isb);
    } else {
      int o = tid - 30;
      for (int m = 0; m < HID; ++m) a += ldin(lg1b, m, isb) * ldin(lg2w, (long)m * 4 + o, isb);
      a += ldin(lg2b, o, isb);
    }
    comb_b[tid] = a;
  }
}

// proj[b][h][t] = sum_c feat[b][c][t] * i2h[c][h], stored f16
__global__ void k_proj(const void* fea, const __half* i2h16, __half* proj, const int* flag) {
  int isb = flag[0];
  int b = blockIdx.x >> 2;
  int tc = blockIdx.x & 3;
  int t = tc * 256 + threadIdx.x;
  const long fb = ((long)b * CDIM) * TT + t;
  for (int hc = 0; hc < 16; ++hc) {
    float acc[16];
#pragma unroll
    for (int j = 0; j < 16; ++j) acc[j] = 0.f;
    for (int c = 0; c < CDIM; ++c) {
      float f = ldin(fea, fb + (long)c * TT, isb);
#pragma unroll
      for (int j = 0; j < 16; ++j) acc[j] += f * __half2float(i2h16[c * HID + hc * 16 + j]);
    }
#pragma unroll
    for (int j = 0; j < 16; ++j)
      proj[((long)b * HID + hc * 16 + j) * TT + t] = __float2half(acc[j]);
  }
}

// ---------------- main persistent decode kernel: 64 blocks x 1024 threads ----------------
__global__ __launch_bounds__(1024, 1) void k_main(
    const __half2* proj2, const __half2* feat2, const void* fea, const int* targets,
    const __half2* h2h2, const float* h2hbf, const __half2* wih2, const __half2* whh2,
    const float* bihf, const float* bhhf, const float* scoref, const float* comb_w,
    const float* comb_b, void* out, const int* flag, int steps, int tierA, TanhC tc) {
  const int tid = threadIdx.x;
  const int b = blockIdx.x;
  const int lane = tid & 63, wid = tid >> 6;
  const int isb = flag[0];

  __shared__ float sh_hidden[HID];
  __shared__ __align__(8) __half2 sh_phsc[HID];   // (ph, score) per h
  __shared__ __align__(8) __half2 sh_alpha2[TP];  // normalized alpha pairs
  __shared__ float sh_alphaf[TT];                 // tier B fallback
  __shared__ float sh_ctx[CDIM];
  __shared__ __align__(8) __half2 sh_x2[XP + 1];
  __shared__ __align__(8) __half2 sh_h2[HP];
  __shared__ float sh_gx[GDIM];
  __shared__ float sh_gh[GDIM];
  __shared__ float sh_red[16];
  __shared__ float sh_bc;

  __half my_sc = __float2half(0.f);
  if (tid < HID) {
    my_sc = __float2half(scoref[tid]);
    sh_hidden[tid] = 0.f;
  }
  if (tid < HP) sh_h2[tid] = __float2half2_rn(0.f);
  __syncthreads();

  const v2h C0 = v2splat(tc.c[0]), C1 = v2splat(tc.c[1]), C2 = v2splat(tc.c[2]),
            C3 = v2splat(tc.c[3]), C4 = v2splat(tc.c[4]), C5 = v2splat(tc.c[5]),
            C6 = v2splat(tc.c[6]);
  const v2h CLO = v2splat(-3.9f), CHI = v2splat(3.9f);
  const v2h VS = v2splat(0.0625f);

  const __half2* pb = proj2 + (long)b * HID * TP + (tid < TP ? tid : 0);

  for (int step = 0; step < steps; ++step) {
    const int tgt = targets[b * steps + step];

    // ---- A: ph[h] = h2h_b[h] + hidden . h2h_w[:,h]  (f16 pairs + readlane bcast)
    if (tid < HID) {
      unsigned hreg0 = v2u(h2v(sh_h2[lane]));
      unsigned hreg1 = v2u(h2v(sh_h2[lane + 64]));
      float a = h2hbf[tid];
      for (int l = 0; l < 64; ++l) {
        a = f_dot2(u2v(__builtin_amdgcn_readlane(hreg0, l)), h2v(h2h2[l * HID + tid]), a);
      }
      for (int l = 0; l < 64; ++l) {
        a = f_dot2(u2v(__builtin_amdgcn_readlane(hreg1, l)), h2v(h2h2[(64 + l) * HID + tid]), a);
      }
      v2h ps = {(_Float16)a, (_Float16)__half2float(my_sc)};
      sh_phsc[tid] = __builtin_bit_cast(__half2, ps);
    }
    __syncthreads();

    // ---- B: e[t] = sum_h score[h]*tanh(proj[h][t] + ph[h]) ; packed f16 pairs over t
    float e0 = -1e30f, e1 = -1e30f;
    if (tid < TP) {
      float f0 = 0.f, f1 = 0.f;
      for (int hc = 0; hc < 8; ++hc) {
        v2h acc = v2splat(0.f);
#pragma unroll 8
        for (int hi = 0; hi < 32; ++hi) {
          int h = hc * 32 + hi;
          v2h ps = h2v(sh_phsc[h]);
          v2h phb = {ps.x, ps.x};
          v2h scb = {ps.y, ps.y};
          v2h x = h2v(pb[(long)h * TP]) + phb;
          x = __builtin_elementwise_max(x, CLO);
          x = __builtin_elementwise_min(x, CHI);
          v2h v = x * x * VS;
          v2h p = C6;
          p = p * v + C5;
          p = p * v + C4;
          p = p * v + C3;
          p = p * v + C2;
          p = p * v + C1;
          p = p * v + C0;
          v2h th = p * x;
          acc = acc + scb * th;
        }
        f0 += (float)acc.x;
        f1 += (float)acc.y;
      }
      e0 = f0;
      e1 = f1;
    }

    // ---- C: softmax over 1024
    float m = fmaxf(e0, e1);
#pragma unroll
    for (int off = 32; off > 0; off >>= 1) m = fmaxf(m, __shfl_xor(m, off, 64));
    if (lane == 0) sh_red[wid] = m;
    __syncthreads();
    if (tid < 64) {
      float mm = (tid < 16) ? sh_red[tid] : -1e30f;
#pragma unroll
      for (int off = 8; off > 0; off >>= 1) mm = fmaxf(mm, __shfl_xor(mm, off, 64));
      if (tid == 0) sh_bc = mm;
    }
    __syncthreads();
    m = sh_bc;
    float p0 = (tid < TP) ? exp2f((e0 - m) * 1.44269504f) : 0.f;
    float p1 = (tid < TP) ? exp2f((e1 - m) * 1.44269504f) : 0.f;
    float s = p0 + p1;
#pragma unroll
    for (int off = 32; off > 0; off >>= 1) s += __shfl_xor(s, off, 64);
    if (lane == 0) sh_red[wid] = s;
    __syncthreads();
    if (tid < 64) {
      float ss = (tid < 16) ? sh_red[tid] : 0.f;
#pragma unroll
      for (int off = 8; off > 0; off >>= 1) ss += __shfl_xor(ss, off, 64);
      if (tid == 0) sh_bc = ss;
    }
    __syncthreads();
    float rs = 1.0f / sh_bc;
    if (tid < TP) {
      sh_alpha2[tid] = __floats2half2_rn(p0 * rs, p1 * rs);
      if (!tierA) {
        sh_alphaf[2 * tid] = p0 * rs;
        sh_alphaf[2 * tid + 1] = p1 * rs;
      }
    }
    __syncthreads();

    // ---- D: context[c] = sum_t alpha[t]*feat[c][t]; wave-per-c, alpha in VGPRs
    if (tierA) {
      uint2 av[4];
      const uint2* al2 = (const uint2*)sh_alpha2;
#pragma unroll
      for (int k = 0; k < 4; ++k) av[k] = al2[lane + 64 * k];
      const uint2* fb2 = (const uint2*)(feat2 + (long)b * CDIM * TP);
      for (int c = wid; c < CDIM; c += 16) {
        const uint2* fr = fb2 + (long)c * (TP / 2) + lane;
        float a = 0.f;
#pragma unroll
        for (int k = 0; k < 4; ++k) {
          uint2 f = fr[64 * k];
          a = f_dot2(u2v(f.x), u2v(av[k].x), a);
          a = f_dot2(u2v(f.y), u2v(av[k].y), a);
        }
        a = wave_sum64(a);
        if (lane == 63) sh_ctx[c] = a;
      }
    } else {
      for (int c = wid; c < CDIM; c += 16) {
        long base = ((long)b * CDIM + c) * TT + lane;
        float a = 0.f;
#pragma unroll
        for (int k = 0; k < 16; ++k) a += ldin(fea, base + 64 * k, isb) * sh_alphaf[lane + 64 * k];
        a = wave_sum64(a);
        if (lane == 63) sh_ctx[c] = a;
      }
    }
    __syncthreads();

    // ---- E: pack x = [context, onehot(tgt)] into half2 pairs
    if (tid < 256) {
      sh_x2[tid] = __floats2half2_rn(sh_ctx[2 * tid], sh_ctx[2 * tid + 1]);
    } else if (tid < XP) {
      int k0 = 2 * tid - CDIM;
      sh_x2[tid] = __floats2half2_rn(k0 == tgt ? 1.f : 0.f, (k0 + 1) == tgt ? 1.f : 0.f);
    }
    __syncthreads();

    // ---- F: GRU gate pre-activations (768 cols)
    if (tid < GDIM) {
      unsigned xr[5];
#pragma unroll
      for (int k = 0; k < 5; ++k) {
        int idx = lane + 64 * k;
        xr[k] = (idx < XP) ? v2u(h2v(sh_x2[idx])) : 0u;
      }
      unsigned hr0 = v2u(h2v(sh_h2[lane]));
      unsigned hr1 = v2u(h2v(sh_h2[lane + 64]));
      float gx = bihf[tid];
      float gh = bhhf[tid];
      const __half2* wp = wih2 + tid;
#pragma unroll
      for (int k = 0; k < 5; ++k) {
        const int lim = (k == 4) ? (XP - 256) : 64;
        for (int l = 0; l < lim; ++l) {
          gx = f_dot2(u2v(__builtin_amdgcn_readlane(xr[k], l)), h2v(wp[(64 * k + l) * GDIM]), gx);
        }
      }
      const __half2* hp = whh2 + tid;
      for (int l = 0; l < 64; ++l)
        gh = f_dot2(u2v(__builtin_amdgcn_readlane(hr0, l)), h2v(hp[l * GDIM]), gh);
      for (int l = 0; l < 64; ++l)
        gh = f_dot2(u2v(__builtin_amdgcn_readlane(hr1, l)), h2v(hp[(64 + l) * GDIM]), gh);
      sh_gx[tid] = gx;
      sh_gh[tid] = gh;
    }
    __syncthreads();

    // ---- G: GRU combine -> new hidden
    if (tid < HID) {
      float xrv = sh_gx[tid], xz = sh_gx[tid + HID], xn = sh_gx[tid + 2 * HID];
      float hrv = sh_gh[tid], hz = sh_gh[tid + HID], hn = sh_gh[tid + 2 * HID];
      float r = 1.f / (1.f + __expf(-(xrv + hrv)));
      float z = 1.f / (1.f + __expf(-(xz + hz)));
      float n = tanhf(xn + r * hn);
      sh_hidden[tid] = (1.f - z) * n + z * sh_hidden[tid];
    }
    __syncthreads();

    // ---- H: outputs + repack h2 for next step
    if (tid >= 64 && tid < 64 + HP) {
      int t2 = tid - 64;
      sh_h2[t2] = __floats2half2_rn(sh_hidden[2 * t2], sh_hidden[2 * t2 + 1]);
    }
    float hv[4];
    if (tid < 64) {
#pragma unroll
      for (int k = 0; k < 4; ++k) hv[k] = sh_hidden[lane + 64 * k];
    }
    if (tid < 34) {
      float a = comb_b[tid];
#pragma unroll
      for (int k = 0; k < 4; ++k) {
        for (int l = 0; l < 64; ++l) {
          float h = __builtin_bit_cast(
              float, __builtin_amdgcn_readlane(__builtin_bit_cast(int, hv[k]), l));
          a += h * comb_w[(64 * k + l) * 34 + tid];
        }
      }
      long so;
      float vv;
      if (tid < 30) {
        so = ((long)b * steps + step) * 30 + tid;
        vv = a;
      } else {
        so = (long)BB * steps * 30 + ((long)b * steps + step) * 4 + (tid - 30);
        vv = 1.f / (1.f + __expf(-a));
      }
      if (isb)
        ((__hip_bfloat16*)out)[so] = __float2bfloat16(vv);
      else
        ((float*)out)[so] = vv;
    }
    __syncthreads();
  }
}

// ---------------- host: tanh poly fit (deg-6 in v = x^2/16, odd deg-13 in x) ----------------
static void fit_tanh(float cf[7]) {
  double A[7][7] = {{0}}, r[7] = {0};
  const int N = 1024;
  for (int i = 1; i <= N; ++i) {
    double x = 3.9 * i / N;
    double v = (x * x) / 16.0;
    double t = tanh(x);
    double phi[7];
    double pw = x;
    for (int j = 0; j < 7; ++j) {
      phi[j] = pw;
      pw *= v;
    }
    for (int j = 0; j < 7; ++j) {
      r[j] += phi[j] * t;
      for (int k = 0; k < 7; ++k) A[j][k] += phi[j] * phi[k];
    }
  }
  for (int col = 0; col < 7; ++col) {
    int piv = col;
    for (int rr = col + 1; rr < 7; ++rr)
      if (fabs(A[rr][col]) > fabs(A[piv][col])) piv = rr;
    if (piv != col) {
      for (int k = 0; k < 7; ++k) {
        double tmp = A[col][k];
        A[col][k] = A[piv][k];
        A[piv][k] = tmp;
      }
      double tb = r[col];
      r[col] = r[piv];
      r[piv] = tb;
    }
    double d = A[col][col];
    for (int rr = col + 1; rr < 7; ++rr) {
      double f = A[rr][col] / d;
      for (int k = col; k < 7; ++k) A[rr][k] -= f * A[col][k];
      r[rr] -= f * r[col];
    }
  }
  double c[7];
  for (int col = 6; col >= 0; --col) {
    double ss = r[col];
    for (int k = col + 1; k < 7; ++k) ss -= A[col][k] * c[k];
    c[col] = ss / A[col][col];
  }
  for (int j = 0; j < 7; ++j) cf[j] = (float)c[j];
}

extern "C" void kernel_launch(void* const* d_in, const int* in_sizes, int n_in, void* d_out,
                              int out_size, void* d_ws, size_t ws_size, hipStream_t stream) {
  (void)n_in;
  (void)out_size;
  const void* fea = d_in[0];
  const int* targets = (const int*)d_in[1];
  const void* i2h_w = d_in[2];
  const void* h2h_w = d_in[3];
  const void* h2h_b = d_in[4];
  const void* score_w = d_in[5];
  const void* gru_w_ih = d_in[6];
  const void* gru_w_hh = d_in[7];
  const void* gru_b_ih = d_in[8];
  const void* gru_b_hh = d_in[9];
  const void* sg1_w = d_in[10];
  const void* sg1_b = d_in[11];
  const void* sg2_w = d_in[12];
  const void* sg2_b = d_in[13];
  const void* lg1_w = d_in[14];
  const void* lg1_b = d_in[15];
  const void* lg2_w = d_in[16];
  const void* lg2_b = d_in[17];
  const int steps = in_sizes[1] / BB;  // 501

  char* p = (char*)d_ws;
  auto alloc = [&](size_t bytes) {
    char* r = p;
    p += (bytes + 255) & ~(size_t)255;
    return r;
  };
  __half* proj16 = (__half*)alloc((size_t)BB * HID * TT * 2);
  __half* i2h16 = (__half*)alloc((size_t)CDIM * HID * 2);
  __half2* h2h2 = (__half2*)alloc((size_t)128 * 256 * 4);
  __half2* wih2 = (__half2*)alloc((size_t)XP * GDIM * 4);
  __half2* whh2 = (__half2*)alloc((size_t)HP * GDIM * 4);
  float* scoref = (float*)alloc(256 * 4);
  float* h2hbf = (float*)alloc(256 * 4);
  float* bihf = (float*)alloc(768 * 4);
  float* bhhf = (float*)alloc(768 * 4);
  float* combw = (float*)alloc(256 * 34 * 4);
  float* combb = (float*)alloc(64 * 4);
  int* flag = (int*)alloc(256);
  __half* feat16 = nullptr;
  int tierA = 0;
  size_t used = (size_t)(p - (char*)d_ws);
  if (used + (size_t)BB * CDIM * TT * 2 + 256 <= ws_size) {
    feat16 = (__half*)alloc((size_t)BB * CDIM * TT * 2);
    tierA = 1;
  }

  TanhC tc;
  fit_tanh(tc.c);

  k_sniff<<<1, 256, 0, stream>>>(fea, flag);
  k_cvt_h<<<256, 256, 0, stream>>>(i2h_w, i2h16, (long)CDIM * HID, flag);
  k_pair<<<128, 256, 0, stream>>>(h2h_w, h2h2, 128, 256, flag);
  k_pair<<<814, 256, 0, stream>>>(gru_w_ih, wih2, XP, GDIM, flag);
  k_pair<<<384, 256, 0, stream>>>(gru_w_hh, whh2, HP, GDIM, flag);
  k_cvt_f<<<1, 256, 0, stream>>>(score_w, scoref, 256, flag);
  k_cvt_f<<<1, 256, 0, stream>>>(h2h_b, h2hbf, 256, flag);
  k_cvt_f<<<3, 256, 0, stream>>>(gru_b_ih, bihf, 768, flag);
  k_cvt_f<<<3, 256, 0, stream>>>(gru_b_hh, bhhf, 768, flag);
  k_comb<<<1, 256, 0, stream>>>(sg1_w, sg1_b, sg2_w, sg2_b, lg1_w, lg1_b, lg2_w, lg2_b, combw,
                                combb, flag);
  if (tierA) k_cvt_h<<<2048, 256, 0, stream>>>(fea, feat16, (long)BB * CDIM * TT, flag);
  k_proj<<<256, 256, 0, stream>>>(fea, i2h16, proj16, flag);

  k_main<<<BB, 1024, 0, stream>>>((const __half2*)proj16, (const __half2*)feat16, fea, targets,
                                  h2h2, h2hbf, wih2, whh2, bihf, bhhf, scoref, combw, combb,
                                  d_out, flag, steps, tierA, tc);
}

// Round 3
// 36705.725 us; speedup vs baseline: 3.3471x; 3.3471x over previous
//
#include <hip/hip_runtime.h>
#include <hip/hip_bf16.h>
#include <hip/hip_fp16.h>
#include <math.h>

#define BB 64
#define CDIM 512
#define TT 1024
#define TP 512
#define HID 256
#define NEMB 30
#define GDIM 768
#define XP 271
#define HP 128

typedef _Float16 v2h __attribute__((ext_vector_type(2)));

struct TanhC { float c[7]; };

__device__ inline float f_dot2(v2h a, v2h b, float c) {
#if __has_builtin(__builtin_amdgcn_fdot2)
  return __builtin_amdgcn_fdot2(a, b, c, false);
#else
  return c + (float)a.x * (float)b.x + (float)a.y * (float)b.y;
#endif
}

__device__ inline v2h u2v(unsigned u) { return __builtin_bit_cast(v2h, u); }
__device__ inline unsigned v2u(v2h h) { return __builtin_bit_cast(unsigned, h); }
__device__ inline v2h h2v(__half2 h) { return __builtin_bit_cast(v2h, h); }
__device__ inline v2h v2splat(float f) {
  _Float16 h = (_Float16)f;
  v2h r = {h, h};
  return r;
}

// input loader: isb=1 -> bf16, else f32
__device__ inline float ldin(const void* p, long i, int isb) {
  if (isb) {
    unsigned u = ((const unsigned short*)p)[i];
    return __uint_as_float(u << 16);
  }
  return ((const float*)p)[i];
}

template <int CTRL, int RM, int BM, bool BC>
__device__ inline float dpp_add(float v) {
  int m = __builtin_amdgcn_update_dpp(0, __builtin_bit_cast(int, v), CTRL, RM, BM, BC);
  return v + __builtin_bit_cast(float, m);
}
// full wave64 sum; result valid in lane 63
__device__ inline float wave_sum64(float v) {
  v = dpp_add<0x111, 0xf, 0xf, true>(v);
  v = dpp_add<0x112, 0xf, 0xf, true>(v);
  v = dpp_add<0x114, 0xf, 0xe, false>(v);
  v = dpp_add<0x118, 0xf, 0xc, false>(v);
  v = dpp_add<0x142, 0xa, 0xf, false>(v);
  v = dpp_add<0x143, 0xc, 0xf, false>(v);
  return v;
}

// ---------------- dtype sniffer ----------------
__global__ void k_sniff(const void* fea, int* flag) {
  __shared__ int s[256];
  int tid = threadIdx.x;
  const unsigned short* u16 = (const unsigned short*)fea;
  int cnt = 0;
  for (int i = tid; i < 2048; i += 256) {
    unsigned u = u16[2 * i];
    float v = __uint_as_float(u << 16);
    float a = fabsf(v);
    if (a > 1e-6f && a < 16.0f) cnt++;
  }
  s[tid] = cnt;
  __syncthreads();
  for (int off = 128; off > 0; off >>= 1) {
    if (tid < off) s[tid] += s[tid + off];
    __syncthreads();
  }
  if (tid == 0) flag[0] = (s[0] > 1024) ? 1 : 0;
}

// ---------------- converters ----------------
__global__ void k_cvt_h(const void* src, __half* dst, long n, const int* flag) {
  int isb = flag[0];
  long i = (long)blockIdx.x * blockDim.x + threadIdx.x;
  long stride = (long)gridDim.x * blockDim.x;
  for (; i < n; i += stride) dst[i] = __float2half(ldin(src, i, isb));
}

__global__ void k_cvt_f(const void* src, float* dst, long n, const int* flag) {
  int isb = flag[0];
  long i = (long)blockIdx.x * blockDim.x + threadIdx.x;
  long stride = (long)gridDim.x * blockDim.x;
  for (; i < n; i += stride) dst[i] = ldin(src, i, isb);
}

// pack row pairs: dst[cp*cols + j] = (src[2cp][j], src[2cp+1][j])
__global__ void k_pair(const void* src, __half2* dst, int pairs, int cols, const int* flag) {
  int isb = flag[0];
  long n = (long)pairs * cols;
  long i = (long)blockIdx.x * blockDim.x + threadIdx.x;
  long stride = (long)gridDim.x * blockDim.x;
  for (; i < n; i += stride) {
    long cp = i / cols, j = i % cols;
    dst[i] = __floats2half2_rn(ldin(src, (2 * cp) * (long)cols + j, isb),
                               ldin(src, (2 * cp + 1) * (long)cols + j, isb));
  }
}

// combined output head
__global__ void k_comb(const void* sg1w, const void* sg1b, const void* sg2w, const void* sg2b,
                       const void* lg1w, const void* lg1b, const void* lg2w, const void* lg2b,
                       float* comb_w, float* comb_b, const int* flag) {
  int isb = flag[0];
  int tid = threadIdx.x;
  float acc[34];
#pragma unroll
  for (int o = 0; o < 34; ++o) acc[o] = 0.f;
  for (int m = 0; m < HID; ++m) {
    float s1 = ldin(sg1w, (long)tid * HID + m, isb);
    float l1 = ldin(lg1w, (long)tid * HID + m, isb);
#pragma unroll
    for (int o = 0; o < 30; ++o) acc[o] += s1 * ldin(sg2w, (long)m * NEMB + o, isb);
#pragma unroll
    for (int o = 0; o < 4; ++o) acc[30 + o] += l1 * ldin(lg2w, (long)m * 4 + o, isb);
  }
  for (int o = 0; o < 34; ++o) comb_w[tid * 34 + o] = acc[o];
  if (tid < 34) {
    float a = 0.f;
    if (tid < 30) {
      for (int m = 0; m < HID; ++m) a += ldin(sg1b, m, isb) * ldin(sg2w, (long)m * NEMB + tid, isb);
      a += ldin(sg2b, tid, isb);
    } else {
      int o = tid - 30;
      for (int m = 0; m < HID; ++m) a += ldin(lg1b, m, isb) * ldin(lg2w, (long)m * 4 + o, isb);
      a += ldin(lg2b, o, isb);
    }
    comb_b[tid] = a;
  }
}

// proj[b][h][t] = sum_c feat[b][c][t] * i2h[c][h], stored f16
__global__ void k_proj(const void* fea, const __half* i2h16, __half* proj, const int* flag) {
  int isb = flag[0];
  int b = blockIdx.x >> 2;
  int tc = blockIdx.x & 3;
  int t = tc * 256 + threadIdx.x;
  const long fb = ((long)b * CDIM) * TT + t;
  for (int hc = 0; hc < 16; ++hc) {
    float acc[16];
#pragma unroll
    for (int j = 0; j < 16; ++j) acc[j] = 0.f;
    for (int c = 0; c < CDIM; ++c) {
      float f = ldin(fea, fb + (long)c * TT, isb);
#pragma unroll
      for (int j = 0; j < 16; ++j) acc[j] += f * __half2float(i2h16[c * HID + hc * 16 + j]);
    }
#pragma unroll
    for (int j = 0; j < 16; ++j)
      proj[((long)b * HID + hc * 16 + j) * TT + t] = __float2half(acc[j]);
  }
}

// FW2[b][tp][col] = half2( sum_c fea[b][c][2tp]*Wih[c][col], sum_c fea[b][c][2tp+1]*Wih[c][col] )
// block = b*512 + tp, 768 threads (col)
__global__ void k_fw(const void* fea, const __half2* wih2, __half2* fw2, const int* flag) {
  int isb = flag[0];
  int blk = blockIdx.x;
  int b = blk >> 9;
  int tp = blk & 511;
  int col = threadIdx.x;
  long fbase = ((long)b * CDIM) * TT + 2 * tp;
  float a0 = 0.f, a1 = 0.f;
  for (int cp = 0; cp < 256; ++cp) {
    float f00 = ldin(fea, fbase + (long)(2 * cp) * TT, isb);
    float f01 = ldin(fea, fbase + (long)(2 * cp) * TT + 1, isb);
    float f10 = ldin(fea, fbase + (long)(2 * cp + 1) * TT, isb);
    float f11 = ldin(fea, fbase + (long)(2 * cp + 1) * TT + 1, isb);
    v2h xa = {(_Float16)f00, (_Float16)f10};
    v2h xb = {(_Float16)f01, (_Float16)f11};
    v2h w = h2v(wih2[cp * GDIM + col]);
    a0 = f_dot2(xa, w, a0);
    a1 = f_dot2(xb, w, a1);
  }
  v2h r = {(_Float16)a0, (_Float16)a1};
  fw2[((long)b * 512 + tp) * GDIM + col] = __builtin_bit_cast(__half2, r);
}

// w4[l][col], col<256: h2h pair-rows; col>=256: whh pair-rows (col-256)
__global__ void k_w4(const void* h2hw, const void* whhw, __half2* w4, const int* flag) {
  int isb = flag[0];
  int idx = blockIdx.x * 256 + threadIdx.x;  // 512 blocks x 256
  int l = idx >> 10, col = idx & 1023;
  float a, b2;
  if (col < 256) {
    a = ldin(h2hw, (long)(2 * l) * 256 + col, isb);
    b2 = ldin(h2hw, (long)(2 * l + 1) * 256 + col, isb);
  } else {
    int j = col - 256;
    a = ldin(whhw, (long)(2 * l) * GDIM + j, isb);
    b2 = ldin(whhw, (long)(2 * l + 1) * GDIM + j, isb);
  }
  w4[idx] = __floats2half2_rn(a, b2);
}

__global__ void k_bias4(const void* h2hb, const void* bhh, float* bias4, const int* flag) {
  int isb = flag[0];
  int col = blockIdx.x * 256 + threadIdx.x;  // 4 blocks
  bias4[col] = (col < 256) ? ldin(h2hb, col, isb) : ldin(bhh, col - 256, isb);
}

// embb[e][col] = Wih[512+e][col] + b_ih[col]
__global__ void k_embb(const void* wih, const void* bih, float* embb, const int* flag) {
  int isb = flag[0];
  int idx = blockIdx.x * 256 + threadIdx.x;  // 90 blocks
  if (idx >= NEMB * GDIM) return;
  int e = idx / GDIM, col = idx % GDIM;
  embb[idx] = ldin(wih, (long)(512 + e) * GDIM + col, isb) + ldin(bih, col, isb);
}

// ---------------- NEW main kernel (FW mode): 64 blocks x 1024 threads ----------------
__global__ __launch_bounds__(1024, 1) void k_main_fw(
    const __half2* proj2, const __half2* fw2, const int* targets, const __half2* w4,
    const float* bias4, const float* embb, const float* scoref, const float* comb_w,
    const float* comb_b, void* out, const int* flag, int steps, TanhC tc) {
  const int tid = threadIdx.x;
  const int b = blockIdx.x;
  const int lane = tid & 63, wid = tid >> 6;
  const int isb = flag[0];

  __shared__ float sh_pa[4096];                   // phase partials (A / B / D')
  __shared__ __align__(8) __half2 sh_phsc[HID];   // (ph, score)
  __shared__ __align__(8) __half2 sh_alpha2[TP];  // alpha pairs
  __shared__ float sh_gh[GDIM];
  __shared__ float sh_hidden[HID];
  __shared__ __align__(8) __half2 sh_h2[HP];
  __shared__ float sh_red[16];
  __shared__ float sh_bc;

  __half my_sc = __float2half(0.f);
  if (tid < HID) {
    my_sc = __float2half(scoref[tid]);
    sh_hidden[tid] = 0.f;
  }
  if (tid < HP) sh_h2[tid] = __float2half2_rn(0.f);
  __syncthreads();

  const v2h C0 = v2splat(tc.c[0]), C1 = v2splat(tc.c[1]), C2 = v2splat(tc.c[2]),
            C3 = v2splat(tc.c[3]), C4 = v2splat(tc.c[4]), C5 = v2splat(tc.c[5]),
            C6 = v2splat(tc.c[6]);
  const v2h CLO = v2splat(-3.9f), CHI = v2splat(3.9f);
  const v2h VS = v2splat(0.0625f);

  const __half2* pbase = proj2 + (long)b * HID * TP;
  const __half2* fwb = fw2 + (long)b * 512 * GDIM;

  for (int step = 0; step < steps; ++step) {
    const int tgt = targets[b * steps + step];

    // ---- A: [ph | gh] = h @ [h2h | whh] + bias4 ; 1024 cols, 4 row-chunks of 32 pair-rows
    {
      const int chunk = tid >> 8;          // 0..3
      const int c4 = (tid & 255) << 2;     // col group of 4
      float a0 = 0.f, a1 = 0.f, a2 = 0.f, a3 = 0.f;
      const uint4* wr = (const uint4*)(w4 + (long)(chunk * 32) * 1024 + c4);
#pragma unroll 4
      for (int i = 0; i < 32; ++i) {
        v2h hp = h2v(sh_h2[chunk * 32 + i]);
        uint4 w = wr[i * 256];  // (1024 half2)/4 per row
        a0 = f_dot2(hp, u2v(w.x), a0);
        a1 = f_dot2(hp, u2v(w.y), a1);
        a2 = f_dot2(hp, u2v(w.z), a2);
        a3 = f_dot2(hp, u2v(w.w), a3);
      }
      float4* dst = (float4*)&sh_pa[chunk * 1024 + c4];
      *dst = make_float4(a0, a1, a2, a3);
    }
    __syncthreads();
    {
      float v = sh_pa[tid] + sh_pa[1024 + tid] + sh_pa[2048 + tid] + sh_pa[3072 + tid] +
                bias4[tid];
      if (tid < 256) {
        v2h ps = {(_Float16)v, (_Float16)__half2float(my_sc)};
        sh_phsc[tid] = __builtin_bit_cast(__half2, ps);
      } else {
        sh_gh[tid - 256] = v;
      }
    }
    __syncthreads();

    // ---- B: e[t] partials; thread = (t-pair, h-half)
    {
      const int tp = tid & 511;
      const int hh = tid >> 9;  // 0..1 -> h range hh*128..+128
      const __half2* pb = pbase + tp;
      float f0 = 0.f, f1 = 0.f;
      for (int hc = 0; hc < 4; ++hc) {
        v2h acc = v2splat(0.f);
#pragma unroll 8
        for (int hi = 0; hi < 32; ++hi) {
          int h = hh * 128 + hc * 32 + hi;
          v2h ps = h2v(sh_phsc[h]);
          v2h phb = {ps.x, ps.x};
          v2h scb = {ps.y, ps.y};
          v2h x = h2v(pb[(long)h * TP]) + phb;
          x = __builtin_elementwise_max(x, CLO);
          x = __builtin_elementwise_min(x, CHI);
          v2h v = x * x * VS;
          v2h p = C6;
          p = p * v + C5;
          p = p * v + C4;
          p = p * v + C3;
          p = p * v + C2;
          p = p * v + C1;
          p = p * v + C0;
          acc = acc + scb * (p * x);
        }
        f0 += (float)acc.x;
        f1 += (float)acc.y;
      }
      sh_pa[(hh * 512 + tp) * 2] = f0;
      sh_pa[(hh * 512 + tp) * 2 + 1] = f1;
    }
    __syncthreads();

    // ---- C: softmax (no max pass; |e| is small by construction)
    float p0 = 0.f, p1 = 0.f;
    if (tid < TP) {
      float e0 = sh_pa[tid * 2] + sh_pa[(512 + tid) * 2];
      float e1 = sh_pa[tid * 2 + 1] + sh_pa[(512 + tid) * 2 + 1];
      p0 = exp2f(e0 * 1.44269504f);
      p1 = exp2f(e1 * 1.44269504f);
      float s = p0 + p1;
#pragma unroll
      for (int off = 32; off > 0; off >>= 1) s += __shfl_xor(s, off, 64);
      if (lane == 0) sh_red[wid] = s;
    }
    __syncthreads();
    if (tid < 64) {
      float ss = (tid < 8) ? sh_red[tid] : 0.f;
#pragma unroll
      for (int off = 4; off > 0; off >>= 1) ss += __shfl_xor(ss, off, 64);
      if (tid == 0) sh_bc = ss;
    }
    __syncthreads();
    if (tid < TP) {
      float rs = 1.0f / sh_bc;
      sh_alpha2[tid] = __floats2half2_rn(p0 * rs, p1 * rs);
    }
    __syncthreads();

    // ---- D': gx[col] = sum_tp fdot2(alpha2[tp], FW2[tp][col]) ; 768 threads, 4 t-chunks
    if (tid < 768) {
      const int chunk = tid / 192;         // 0..3, tp range chunk*128..+128
      const int c4 = (tid % 192) << 2;
      float a0 = 0.f, a1 = 0.f, a2 = 0.f, a3 = 0.f;
      const uint4* fr = (const uint4*)(fwb + (long)(chunk * 128) * GDIM + c4);
#pragma unroll 4
      for (int i = 0; i < 128; ++i) {
        v2h al = h2v(sh_alpha2[chunk * 128 + i]);
        uint4 w = fr[i * 192];  // 768/4 uint4 per row
        a0 = f_dot2(al, u2v(w.x), a0);
        a1 = f_dot2(al, u2v(w.y), a1);
        a2 = f_dot2(al, u2v(w.z), a2);
        a3 = f_dot2(al, u2v(w.w), a3);
      }
      float4* dst = (float4*)&sh_pa[chunk * 768 + c4];
      *dst = make_float4(a0, a1, a2, a3);
    }
    __syncthreads();

    // ---- G: combine gates -> h_new
    if (tid < HID) {
      const float* eb = embb + (long)tgt * GDIM;
      float gxr = sh_pa[tid] + sh_pa[768 + tid] + sh_pa[1536 + tid] + sh_pa[2304 + tid] + eb[tid];
      int c1 = tid + 256;
      float gxz = sh_pa[c1] + sh_pa[768 + c1] + sh_pa[1536 + c1] + sh_pa[2304 + c1] + eb[c1];
      int c2 = tid + 512;
      float gxn = sh_pa[c2] + sh_pa[768 + c2] + sh_pa[1536 + c2] + sh_pa[2304 + c2] + eb[c2];
      float hrv = sh_gh[tid], hz = sh_gh[c1], hn = sh_gh[c2];
      float r = 1.f / (1.f + __expf(-(gxr + hrv)));
      float z = 1.f / (1.f + __expf(-(gxz + hz)));
      float n = tanhf(gxn + r * hn);
      sh_hidden[tid] = (1.f - z) * n + z * sh_hidden[tid];
    }
    __syncthreads();

    // ---- H: outputs + repack h2 for next step
    if (tid >= 64 && tid < 64 + HP) {
      int t2 = tid - 64;
      sh_h2[t2] = __floats2half2_rn(sh_hidden[2 * t2], sh_hidden[2 * t2 + 1]);
    }
    float hv[4];
    if (tid < 64) {
#pragma unroll
      for (int k = 0; k < 4; ++k) hv[k] = sh_hidden[lane + 64 * k];
    }
    if (tid < 34) {
      float a = comb_b[tid];
#pragma unroll
      for (int k = 0; k < 4; ++k) {
        for (int l = 0; l < 64; ++l) {
          float h = __builtin_bit_cast(
              float, __builtin_amdgcn_readlane(__builtin_bit_cast(int, hv[k]), l));
          a += h * comb_w[(64 * k + l) * 34 + tid];
        }
      }
      long so;
      float vv;
      if (tid < 30) {
        so = ((long)b * steps + step) * 30 + tid;
        vv = a;
      } else {
        so = (long)BB * steps * 30 + ((long)b * steps + step) * 4 + (tid - 30);
        vv = 1.f / (1.f + __expf(-a));
      }
      if (isb)
        ((__hip_bfloat16*)out)[so] = __float2bfloat16(vv);
      else
        ((float*)out)[so] = vv;
    }
    __syncthreads();
  }
}

// ---------------- OLD main kernel (fallback, passed R2) ----------------
__global__ __launch_bounds__(1024, 1) void k_main(
    const __half2* proj2, const __half2* feat2, const void* fea, const int* targets,
    const __half2* h2h2, const float* h2hbf, const __half2* wih2, const __half2* whh2,
    const float* bihf, const float* bhhf, const float* scoref, const float* comb_w,
    const float* comb_b, void* out, const int* flag, int steps, int tierA, TanhC tc) {
  const int tid = threadIdx.x;
  const int b = blockIdx.x;
  const int lane = tid & 63, wid = tid >> 6;
  const int isb = flag[0];

  __shared__ float sh_hidden[HID];
  __shared__ __align__(8) __half2 sh_phsc[HID];
  __shared__ __align__(8) __half2 sh_alpha2[TP];
  __shared__ float sh_alphaf[TT];
  __shared__ float sh_ctx[CDIM];
  __shared__ __align__(8) __half2 sh_x2[XP + 1];
  __shared__ __align__(8) __half2 sh_h2[HP];
  __shared__ float sh_gx[GDIM];
  __shared__ float sh_gh[GDIM];
  __shared__ float sh_red[16];
  __shared__ float sh_bc;

  __half my_sc = __float2half(0.f);
  if (tid < HID) {
    my_sc = __float2half(scoref[tid]);
    sh_hidden[tid] = 0.f;
  }
  if (tid < HP) sh_h2[tid] = __float2half2_rn(0.f);
  __syncthreads();

  const v2h C0 = v2splat(tc.c[0]), C1 = v2splat(tc.c[1]), C2 = v2splat(tc.c[2]),
            C3 = v2splat(tc.c[3]), C4 = v2splat(tc.c[4]), C5 = v2splat(tc.c[5]),
            C6 = v2splat(tc.c[6]);
  const v2h CLO = v2splat(-3.9f), CHI = v2splat(3.9f);
  const v2h VS = v2splat(0.0625f);

  const __half2* pb = proj2 + (long)b * HID * TP + (tid < TP ? tid : 0);

  for (int step = 0; step < steps; ++step) {
    const int tgt = targets[b * steps + step];

    if (tid < HID) {
      unsigned hreg0 = v2u(h2v(sh_h2[lane]));
      unsigned hreg1 = v2u(h2v(sh_h2[lane + 64]));
      float a = h2hbf[tid];
      for (int l = 0; l < 64; ++l) {
        a = f_dot2(u2v(__builtin_amdgcn_readlane(hreg0, l)), h2v(h2h2[l * HID + tid]), a);
      }
      for (int l = 0; l < 64; ++l) {
        a = f_dot2(u2v(__builtin_amdgcn_readlane(hreg1, l)), h2v(h2h2[(64 + l) * HID + tid]), a);
      }
      v2h ps = {(_Float16)a, (_Float16)__half2float(my_sc)};
      sh_phsc[tid] = __builtin_bit_cast(__half2, ps);
    }
    __syncthreads();

    float e0 = -1e30f, e1 = -1e30f;
    if (tid < TP) {
      float f0 = 0.f, f1 = 0.f;
      for (int hc = 0; hc < 8; ++hc) {
        v2h acc = v2splat(0.f);
#pragma unroll 8
        for (int hi = 0; hi < 32; ++hi) {
          int h = hc * 32 + hi;
          v2h ps = h2v(sh_phsc[h]);
          v2h phb = {ps.x, ps.x};
          v2h scb = {ps.y, ps.y};
          v2h x = h2v(pb[(long)h * TP]) + phb;
          x = __builtin_elementwise_max(x, CLO);
          x = __builtin_elementwise_min(x, CHI);
          v2h v = x * x * VS;
          v2h p = C6;
          p = p * v + C5;
          p = p * v + C4;
          p = p * v + C3;
          p = p * v + C2;
          p = p * v + C1;
          p = p * v + C0;
          v2h th = p * x;
          acc = acc + scb * th;
        }
        f0 += (float)acc.x;
        f1 += (float)acc.y;
      }
      e0 = f0;
      e1 = f1;
    }

    float m = fmaxf(e0, e1);
#pragma unroll
    for (int off = 32; off > 0; off >>= 1) m = fmaxf(m, __shfl_xor(m, off, 64));
    if (lane == 0) sh_red[wid] = m;
    __syncthreads();
    if (tid < 64) {
      float mm = (tid < 16) ? sh_red[tid] : -1e30f;
#pragma unroll
      for (int off = 8; off > 0; off >>= 1) mm = fmaxf(mm, __shfl_xor(mm, off, 64));
      if (tid == 0) sh_bc = mm;
    }
    __syncthreads();
    m = sh_bc;
    float p0 = (tid < TP) ? exp2f((e0 - m) * 1.44269504f) : 0.f;
    float p1 = (tid < TP) ? exp2f((e1 - m) * 1.44269504f) : 0.f;
    float s = p0 + p1;
#pragma unroll
    for (int off = 32; off > 0; off >>= 1) s += __shfl_xor(s, off, 64);
    if (lane == 0) sh_red[wid] = s;
    __syncthreads();
    if (tid < 64) {
      float ss = (tid < 16) ? sh_red[tid] : 0.f;
#pragma unroll
      for (int off = 8; off > 0; off >>= 1) ss += __shfl_xor(ss, off, 64);
      if (tid == 0) sh_bc = ss;
    }
    __syncthreads();
    float rs = 1.0f / sh_bc;
    if (tid < TP) {
      sh_alpha2[tid] = __floats2half2_rn(p0 * rs, p1 * rs);
      if (!tierA) {
        sh_alphaf[2 * tid] = p0 * rs;
        sh_alphaf[2 * tid + 1] = p1 * rs;
      }
    }
    __syncthreads();

    if (tierA) {
      uint2 av[4];
      const uint2* al2 = (const uint2*)sh_alpha2;
#pragma unroll
      for (int k = 0; k < 4; ++k) av[k] = al2[lane + 64 * k];
      const uint2* fb2 = (const uint2*)(feat2 + (long)b * CDIM * TP);
      for (int c = wid; c < CDIM; c += 16) {
        const uint2* fr = fb2 + (long)c * (TP / 2) + lane;
        float a = 0.f;
#pragma unroll
        for (int k = 0; k < 4; ++k) {
          uint2 f = fr[64 * k];
          a = f_dot2(u2v(f.x), u2v(av[k].x), a);
          a = f_dot2(u2v(f.y), u2v(av[k].y), a);
        }
        a = wave_sum64(a);
        if (lane == 63) sh_ctx[c] = a;
      }
    } else {
      for (int c = wid; c < CDIM; c += 16) {
        long base = ((long)b * CDIM + c) * TT + lane;
        float a = 0.f;
#pragma unroll
        for (int k = 0; k < 16; ++k) a += ldin(fea, base + 64 * k, isb) * sh_alphaf[lane + 64 * k];
        a = wave_sum64(a);
        if (lane == 63) sh_ctx[c] = a;
      }
    }
    __syncthreads();

    if (tid < 256) {
      sh_x2[tid] = __floats2half2_rn(sh_ctx[2 * tid], sh_ctx[2 * tid + 1]);
    } else if (tid < XP) {
      int k0 = 2 * tid - CDIM;
      sh_x2[tid] = __floats2half2_rn(k0 == tgt ? 1.f : 0.f, (k0 + 1) == tgt ? 1.f : 0.f);
    }
    __syncthreads();

    if (tid < GDIM) {
      unsigned xr[5];
#pragma unroll
      for (int k = 0; k < 5; ++k) {
        int idx = lane + 64 * k;
        xr[k] = (idx < XP) ? v2u(h2v(sh_x2[idx])) : 0u;
      }
      unsigned hr0 = v2u(h2v(sh_h2[lane]));
      unsigned hr1 = v2u(h2v(sh_h2[lane + 64]));
      float gx = bihf[tid];
      float gh = bhhf[tid];
      const __half2* wp = wih2 + tid;
#pragma unroll
      for (int k = 0; k < 5; ++k) {
        const int lim = (k == 4) ? (XP - 256) : 64;
        for (int l = 0; l < lim; ++l) {
          gx = f_dot2(u2v(__builtin_amdgcn_readlane(xr[k], l)), h2v(wp[(64 * k + l) * GDIM]), gx);
        }
      }
      const __half2* hp = whh2 + tid;
      for (int l = 0; l < 64; ++l)
        gh = f_dot2(u2v(__builtin_amdgcn_readlane(hr0, l)), h2v(hp[l * GDIM]), gh);
      for (int l = 0; l < 64; ++l)
        gh = f_dot2(u2v(__builtin_amdgcn_readlane(hr1, l)), h2v(hp[(64 + l) * GDIM]), gh);
      sh_gx[tid] = gx;
      sh_gh[tid] = gh;
    }
    __syncthreads();

    if (tid < HID) {
      float xrv = sh_gx[tid], xz = sh_gx[tid + HID], xn = sh_gx[tid + 2 * HID];
      float hrv = sh_gh[tid], hz = sh_gh[tid + HID], hn = sh_gh[tid + 2 * HID];
      float r = 1.f / (1.f + __expf(-(xrv + hrv)));
      float z = 1.f / (1.f + __expf(-(xz + hz)));
      float n = tanhf(xn + r * hn);
      sh_hidden[tid] = (1.f - z) * n + z * sh_hidden[tid];
    }
    __syncthreads();

    if (tid >= 64 && tid < 64 + HP) {
      int t2 = tid - 64;
      sh_h2[t2] = __floats2half2_rn(sh_hidden[2 * t2], sh_hidden[2 * t2 + 1]);
    }
    float hv[4];
    if (tid < 64) {
#pragma unroll
      for (int k = 0; k < 4; ++k) hv[k] = sh_hidden[lane + 64 * k];
    }
    if (tid < 34) {
      float a = comb_b[tid];
#pragma unroll
      for (int k = 0; k < 4; ++k) {
        for (int l = 0; l < 64; ++l) {
          float h = __builtin_bit_cast(
              float, __builtin_amdgcn_readlane(__builtin_bit_cast(int, hv[k]), l));
          a += h * comb_w[(64 * k + l) * 34 + tid];
        }
      }
      long so;
      float vv;
      if (tid < 30) {
        so = ((long)b * steps + step) * 30 + tid;
        vv = a;
      } else {
        so = (long)BB * steps * 30 + ((long)b * steps + step) * 4 + (tid - 30);
        vv = 1.f / (1.f + __expf(-a));
      }
      if (isb)
        ((__hip_bfloat16*)out)[so] = __float2bfloat16(vv);
      else
        ((float*)out)[so] = vv;
    }
    __syncthreads();
  }
}

// ---------------- host: tanh poly fit ----------------
static void fit_tanh(float cf[7]) {
  double A[7][7] = {{0}}, r[7] = {0};
  const int N = 1024;
  for (int i = 1; i <= N; ++i) {
    double x = 3.9 * i / N;
    double v = (x * x) / 16.0;
    double t = tanh(x);
    double phi[7];
    double pw = x;
    for (int j = 0; j < 7; ++j) {
      phi[j] = pw;
      pw *= v;
    }
    for (int j = 0; j < 7; ++j) {
      r[j] += phi[j] * t;
      for (int k = 0; k < 7; ++k) A[j][k] += phi[j] * phi[k];
    }
  }
  for (int col = 0; col < 7; ++col) {
    int piv = col;
    for (int rr = col + 1; rr < 7; ++rr)
      if (fabs(A[rr][col]) > fabs(A[piv][col])) piv = rr;
    if (piv != col) {
      for (int k = 0; k < 7; ++k) {
        double tmp = A[col][k];
        A[col][k] = A[piv][k];
        A[piv][k] = tmp;
      }
      double tb = r[col];
      r[col] = r[piv];
      r[piv] = tb;
    }
    double d = A[col][col];
    for (int rr = col + 1; rr < 7; ++rr) {
      double f = A[rr][col] / d;
      for (int k = col; k < 7; ++k) A[rr][k] -= f * A[col][k];
      r[rr] -= f * r[col];
    }
  }
  double c[7];
  for (int col = 6; col >= 0; --col) {
    double ss = r[col];
    for (int k = col + 1; k < 7; ++k) ss -= A[col][k] * c[k];
    c[col] = ss / A[col][col];
  }
  for (int j = 0; j < 7; ++j) cf[j] = (float)c[j];
}

extern "C" void kernel_launch(void* const* d_in, const int* in_sizes, int n_in, void* d_out,
                              int out_size, void* d_ws, size_t ws_size, hipStream_t stream) {
  (void)n_in;
  (void)out_size;
  const void* fea = d_in[0];
  const int* targets = (const int*)d_in[1];
  const void* i2h_w = d_in[2];
  const void* h2h_w = d_in[3];
  const void* h2h_b = d_in[4];
  const void* score_w = d_in[5];
  const void* gru_w_ih = d_in[6];
  const void* gru_w_hh = d_in[7];
  const void* gru_b_ih = d_in[8];
  const void* gru_b_hh = d_in[9];
  const void* sg1_w = d_in[10];
  const void* sg1_b = d_in[11];
  const void* sg2_w = d_in[12];
  const void* sg2_b = d_in[13];
  const void* lg1_w = d_in[14];
  const void* lg1_b = d_in[15];
  const void* lg2_w = d_in[16];
  const void* lg2_b = d_in[17];
  const int steps = in_sizes[1] / BB;  // 501

  char* p = (char*)d_ws;
  auto alloc = [&](size_t bytes) {
    char* r = p;
    p += (bytes + 255) & ~(size_t)255;
    return r;
  };
  __half* proj16 = (__half*)alloc((size_t)BB * HID * TT * 2);
  __half* i2h16 = (__half*)alloc((size_t)CDIM * HID * 2);
  __half2* h2h2 = (__half2*)alloc((size_t)128 * 256 * 4);
  __half2* wih2 = (__half2*)alloc((size_t)XP * GDIM * 4);
  __half2* whh2 = (__half2*)alloc((size_t)HP * GDIM * 4);
  float* scoref = (float*)alloc(256 * 4);
  float* h2hbf = (float*)alloc(256 * 4);
  float* bihf = (float*)alloc(768 * 4);
  float* bhhf = (float*)alloc(768 * 4);
  float* combw = (float*)alloc(256 * 34 * 4);
  float* combb = (float*)alloc(64 * 4);
  int* flag = (int*)alloc(256);
  __half2* w4 = (__half2*)alloc((size_t)128 * 1024 * 4);
  float* bias4 = (float*)alloc(1024 * 4);
  float* embb = (float*)alloc((size_t)NEMB * GDIM * 4);

  size_t used = (size_t)(p - (char*)d_ws);
  const size_t fw_bytes = (size_t)BB * 512 * GDIM * 4;    // 100.7 MB
  const size_t feat_bytes = (size_t)BB * CDIM * TT * 2;   // 67 MB

  __half2* fw2 = nullptr;
  __half* feat16 = nullptr;
  int mode;  // 2 = FW, 1 = tierA, 0 = tierB
  if (used + fw_bytes + 256 <= ws_size) {
    fw2 = (__half2*)alloc(fw_bytes);
    mode = 2;
  } else if (used + feat_bytes + 256 <= ws_size) {
    feat16 = (__half*)alloc(feat_bytes);
    mode = 1;
  } else {
    mode = 0;
  }

  TanhC tc;
  fit_tanh(tc.c);

  k_sniff<<<1, 256, 0, stream>>>(fea, flag);
  k_cvt_h<<<256, 256, 0, stream>>>(i2h_w, i2h16, (long)CDIM * HID, flag);
  k_pair<<<128, 256, 0, stream>>>(h2h_w, h2h2, 128, 256, flag);
  k_pair<<<814, 256, 0, stream>>>(gru_w_ih, wih2, XP, GDIM, flag);
  k_pair<<<384, 256, 0, stream>>>(gru_w_hh, whh2, HP, GDIM, flag);
  k_cvt_f<<<1, 256, 0, stream>>>(score_w, scoref, 256, flag);
  k_cvt_f<<<1, 256, 0, stream>>>(h2h_b, h2hbf, 256, flag);
  k_cvt_f<<<3, 256, 0, stream>>>(gru_b_ih, bihf, 768, flag);
  k_cvt_f<<<3, 256, 0, stream>>>(gru_b_hh, bhhf, 768, flag);
  k_comb<<<1, 256, 0, stream>>>(sg1_w, sg1_b, sg2_w, sg2_b, lg1_w, lg1_b, lg2_w, lg2_b, combw,
                                combb, flag);
  k_w4<<<512, 256, 0, stream>>>(h2h_w, gru_w_hh, w4, flag);
  k_bias4<<<4, 256, 0, stream>>>(h2h_b, gru_b_hh, bias4, flag);
  k_embb<<<90, 256, 0, stream>>>(gru_w_ih, gru_b_ih, embb, flag);
  k_proj<<<256, 256, 0, stream>>>(fea, i2h16, proj16, flag);

  if (mode == 2) {
    k_fw<<<BB * 512, GDIM, 0, stream>>>(fea, wih2, fw2, flag);
    k_main_fw<<<BB, 1024, 0, stream>>>((const __half2*)proj16, fw2, targets, w4, bias4, embb,
                                       scoref, combw, combb, d_out, flag, steps, tc);
  } else {
    if (mode == 1) k_cvt_h<<<2048, 256, 0, stream>>>(fea, feat16, (long)BB * CDIM * TT, flag);
    k_main<<<BB, 1024, 0, stream>>>((const __half2*)proj16, (const __half2*)feat16, fea, targets,
                                    h2h2, h2hbf, wih2, whh2, bihf, bhhf, scoref, combw, combb,
                                    d_out, flag, steps, mode, tc);
  }
}

// Round 4
// 25185.966 us; speedup vs baseline: 4.8780x; 1.4574x over previous
//
#include <hip/hip_runtime.h>
#include <hip/hip_bf16.h>
#include <hip/hip_fp16.h>
#include <math.h>

#define BB 64
#define CDIM 512
#define TT 1024
#define HID 256
#define NEMB 30
#define GDIM 768

typedef _Float16 v2h __attribute__((ext_vector_type(2)));

struct TanhC { float c[7]; };

__device__ inline float f_dot2(v2h a, v2h b, float c) {
  return __builtin_amdgcn_fdot2(a, b, c, false);
}
__device__ inline v2h u2v(unsigned u) { return __builtin_bit_cast(v2h, u); }
__device__ inline unsigned v2u(v2h h) { return __builtin_bit_cast(unsigned, h); }
__device__ inline unsigned packh2(float a, float b) {
  v2h t = {(_Float16)a, (_Float16)b};
  return v2u(t);
}
__device__ inline v2h v2splat(float f) {
  _Float16 h = (_Float16)f;
  v2h r = {h, h};
  return r;
}

// input loader: isb=1 -> bf16, else f32
__device__ inline float ldin(const void* p, long i, int isb) {
  if (isb) {
    unsigned u = ((const unsigned short*)p)[i];
    return __uint_as_float(u << 16);
  }
  return ((const float*)p)[i];
}

template <int CTRL, int RM, int BM, bool BC>
__device__ inline float dpp_add(float v) {
  int m = __builtin_amdgcn_update_dpp(0, __builtin_bit_cast(int, v), CTRL, RM, BM, BC);
  return v + __builtin_bit_cast(float, m);
}
__device__ inline float wave_sum64(float v) {
  v = dpp_add<0x111, 0xf, 0xf, true>(v);
  v = dpp_add<0x112, 0xf, 0xf, true>(v);
  v = dpp_add<0x114, 0xf, 0xe, false>(v);
  v = dpp_add<0x118, 0xf, 0xc, false>(v);
  v = dpp_add<0x142, 0xa, 0xf, false>(v);
  v = dpp_add<0x143, 0xc, 0xf, false>(v);
  return v;
}

// ---------------- dtype sniffer ----------------
__global__ void k_sniff(const void* fea, int* flag) {
  __shared__ int s[256];
  int tid = threadIdx.x;
  const unsigned short* u16 = (const unsigned short*)fea;
  int cnt = 0;
  for (int i = tid; i < 2048; i += 256) {
    unsigned u = u16[2 * i];
    float v = __uint_as_float(u << 16);
    float a = fabsf(v);
    if (a > 1e-6f && a < 16.0f) cnt++;
  }
  s[tid] = cnt;
  __syncthreads();
  for (int off = 128; off > 0; off >>= 1) {
    if (tid < off) s[tid] += s[tid + off];
    __syncthreads();
  }
  if (tid == 0) flag[0] = (s[0] > 1024) ? 1 : 0;
}

__global__ void k_cvt_f(const void* src, float* dst, long n, const int* flag) {
  int isb = flag[0];
  long i = (long)blockIdx.x * blockDim.x + threadIdx.x;
  long stride = (long)gridDim.x * blockDim.x;
  for (; i < n; i += stride) dst[i] = ldin(src, i, isb);
}

// Wc2[cp][col]: pair-rows of [i2h (cols 0-255) | Wih[:512] (cols 256-1023)], half2 bits
__global__ void k_wc(const void* i2h, const void* wih, unsigned* wc2, const int* flag) {
  int isb = flag[0];
  int idx = blockIdx.x * 256 + threadIdx.x;  // 1024 blocks
  int cp = idx >> 10, col = idx & 1023;
  float a, b;
  if (col < 256) {
    a = ldin(i2h, (long)(2 * cp) * 256 + col, isb);
    b = ldin(i2h, (long)(2 * cp + 1) * 256 + col, isb);
  } else {
    int j = col - 256;
    a = ldin(wih, (long)(2 * cp) * GDIM + j, isb);
    b = ldin(wih, (long)(2 * cp + 1) * GDIM + j, isb);
  }
  wc2[idx] = packh2(a, b);
}

// w4[l][col]: pair-rows of [h2h (cols 0-255) | whh (cols 256-1023)]
__global__ void k_w4(const void* h2hw, const void* whhw, unsigned* w4, const int* flag) {
  int isb = flag[0];
  int idx = blockIdx.x * 256 + threadIdx.x;  // 512 blocks
  int l = idx >> 10, col = idx & 1023;
  float a, b2;
  if (col < 256) {
    a = ldin(h2hw, (long)(2 * l) * 256 + col, isb);
    b2 = ldin(h2hw, (long)(2 * l + 1) * 256 + col, isb);
  } else {
    int j = col - 256;
    a = ldin(whhw, (long)(2 * l) * GDIM + j, isb);
    b2 = ldin(whhw, (long)(2 * l + 1) * GDIM + j, isb);
  }
  w4[idx] = packh2(a, b2);
}

__global__ void k_bias4(const void* h2hb, const void* bhh, float* bias4, const int* flag) {
  int isb = flag[0];
  int col = blockIdx.x * 256 + threadIdx.x;  // 4 blocks
  bias4[col] = (col < 256) ? ldin(h2hb, col, isb) : ldin(bhh, col - 256, isb);
}

// embb[e][col] = Wih[512+e][col] + b_ih[col]
__global__ void k_embb(const void* wih, const void* bih, float* embb, const int* flag) {
  int isb = flag[0];
  int idx = blockIdx.x * 256 + threadIdx.x;  // 90 blocks
  if (idx >= NEMB * GDIM) return;
  int e = idx / GDIM, col = idx % GDIM;
  embb[idx] = ldin(wih, (long)(512 + e) * GDIM + col, isb) + ldin(bih, col, isb);
}

// combined output head
__global__ void k_comb(const void* sg1w, const void* sg1b, const void* sg2w, const void* sg2b,
                       const void* lg1w, const void* lg1b, const void* lg2w, const void* lg2b,
                       float* comb_w, float* comb_b, const int* flag) {
  int isb = flag[0];
  int tid = threadIdx.x;
  float acc[34];
#pragma unroll
  for (int o = 0; o < 34; ++o) acc[o] = 0.f;
  for (int m = 0; m < HID; ++m) {
    float s1 = ldin(sg1w, (long)tid * HID + m, isb);
    float l1 = ldin(lg1w, (long)tid * HID + m, isb);
#pragma unroll
    for (int o = 0; o < 30; ++o) acc[o] += s1 * ldin(sg2w, (long)m * NEMB + o, isb);
#pragma unroll
    for (int o = 0; o < 4; ++o) acc[30 + o] += l1 * ldin(lg2w, (long)m * 4 + o, isb);
  }
  for (int o = 0; o < 34; ++o) comb_w[tid * 34 + o] = acc[o];
  if (tid < 34) {
    float a = 0.f;
    if (tid < 30) {
      for (int m = 0; m < HID; ++m) a += ldin(sg1b, m, isb) * ldin(sg2w, (long)m * NEMB + tid, isb);
      a += ldin(sg2b, tid, isb);
    } else {
      int o = tid - 30;
      for (int m = 0; m < HID; ++m) a += ldin(lg1b, m, isb) * ldin(lg2w, (long)m * 4 + o, isb);
      a += ldin(lg2b, o, isb);
    }
    comb_b[tid] = a;
  }
}

// ---------------- tiled GEMM: C[b][t][col] = fea[b][:,t] . Wc[:,col] ----------------
// col<256 -> proj2[b][col][tp] ; col>=256 -> fw2[b][tp][col-256]
__global__ __launch_bounds__(256) void k_gemm(const void* fea, const unsigned* wc2,
                                              unsigned* proj2, unsigned* fw2, const int* flag) {
  const int isb = flag[0];
  const int blk = blockIdx.x;
  const int b = blk >> 6;
  const int tt = (blk >> 3) & 7;
  const int cc = blk & 7;
  const int t0 = tt * 128, c0 = cc * 128;
  __shared__ __align__(16) unsigned At[32][136];
  __shared__ __align__(16) unsigned Wt[32][136];
  const int tid = threadIdx.x;
  const int cp_l = tid >> 3, sg = tid & 7;
  const int tm = tid & 15, tn = tid >> 4;
  float acc[8][8];
#pragma unroll
  for (int i = 0; i < 8; ++i)
#pragma unroll
    for (int jj = 0; jj < 8; ++jj) acc[i][jj] = 0.f;

  for (int kt = 0; kt < 8; ++kt) {
    const int crow = (kt * 32 + cp_l) * 2;
    // stage A: At[cp_l][t-local] = (fea[crow][t], fea[crow+1][t])
    if (isb) {
      const unsigned short* f0p =
          (const unsigned short*)fea + ((long)b * CDIM + crow) * TT + t0 + sg * 16;
      const unsigned short* f1p = f0p + TT;
#pragma unroll
      for (int q = 0; q < 2; ++q) {
        ushort4 u0a = ((const ushort4*)f0p)[2 * q];
        ushort4 u0b = ((const ushort4*)f0p)[2 * q + 1];
        ushort4 u1a = ((const ushort4*)f1p)[2 * q];
        ushort4 u1b = ((const ushort4*)f1p)[2 * q + 1];
        unsigned short a0[8] = {u0a.x, u0a.y, u0a.z, u0a.w, u0b.x, u0b.y, u0b.z, u0b.w};
        unsigned short a1[8] = {u1a.x, u1a.y, u1a.z, u1a.w, u1b.x, u1b.y, u1b.z, u1b.w};
#pragma unroll
        for (int e = 0; e < 8; ++e) {
          float f0 = __uint_as_float(((unsigned)a0[e]) << 16);
          float f1 = __uint_as_float(((unsigned)a1[e]) << 16);
          At[cp_l][sg * 16 + q * 8 + e] = packh2(f0, f1);
        }
      }
    } else {
      const float* f0p = (const float*)fea + ((long)b * CDIM + crow) * TT + t0 + sg * 16;
      const float* f1p = f0p + TT;
#pragma unroll
      for (int q = 0; q < 4; ++q) {
        float4 v0 = ((const float4*)f0p)[q];
        float4 v1 = ((const float4*)f1p)[q];
        At[cp_l][sg * 16 + q * 4 + 0] = packh2(v0.x, v1.x);
        At[cp_l][sg * 16 + q * 4 + 1] = packh2(v0.y, v1.y);
        At[cp_l][sg * 16 + q * 4 + 2] = packh2(v0.z, v1.z);
        At[cp_l][sg * 16 + q * 4 + 3] = packh2(v0.w, v1.w);
      }
    }
    // stage W
    {
      const uint4* wp = (const uint4*)(wc2 + (long)(kt * 32 + cp_l) * 1024 + c0 + sg * 16);
#pragma unroll
      for (int q = 0; q < 4; ++q) {
        uint4 w = wp[q];
        Wt[cp_l][sg * 16 + q * 4 + 0] = w.x;
        Wt[cp_l][sg * 16 + q * 4 + 1] = w.y;
        Wt[cp_l][sg * 16 + q * 4 + 2] = w.z;
        Wt[cp_l][sg * 16 + q * 4 + 3] = w.w;
      }
    }
    __syncthreads();
    for (int cp = 0; cp < 32; ++cp) {
      uint4 aq0 = *(const uint4*)&At[cp][tm * 4];
      uint4 aq1 = *(const uint4*)&At[cp][64 + tm * 4];
      uint4 bq0 = *(const uint4*)&Wt[cp][tn * 4];
      uint4 bq1 = *(const uint4*)&Wt[cp][64 + tn * 4];
      unsigned av[8] = {aq0.x, aq0.y, aq0.z, aq0.w, aq1.x, aq1.y, aq1.z, aq1.w};
      unsigned bv[8] = {bq0.x, bq0.y, bq0.z, bq0.w, bq1.x, bq1.y, bq1.z, bq1.w};
#pragma unroll
      for (int ti = 0; ti < 8; ++ti)
#pragma unroll
        for (int ci = 0; ci < 8; ++ci)
          acc[ti][ci] = f_dot2(u2v(av[ti]), u2v(bv[ci]), acc[ti][ci]);
    }
    __syncthreads();
  }

  // write outputs
#pragma unroll
  for (int q = 0; q < 2; ++q) {
    const int tq = t0 + q * 64 + tm * 4;
#pragma unroll
    for (int pr = 0; pr < 2; ++pr) {
      const int tp = (tq >> 1) + pr;
      const int r0 = q * 4 + 2 * pr, r1 = r0 + 1;
      if (cc < 2) {
#pragma unroll
        for (int ci = 0; ci < 8; ++ci) {
          int h = c0 + tn * 4 + (ci & 3) + ((ci >> 2) << 6);
          proj2[((long)b * HID + h) * 512 + tp] = packh2(acc[r0][ci], acc[r1][ci]);
        }
      } else {
        unsigned* row = fw2 + ((long)b * 512 + tp) * GDIM + (c0 - 256) + tn * 4;
        uint4 pa = {packh2(acc[r0][0], acc[r1][0]), packh2(acc[r0][1], acc[r1][1]),
                    packh2(acc[r0][2], acc[r1][2]), packh2(acc[r0][3], acc[r1][3])};
        uint4 pb = {packh2(acc[r0][4], acc[r1][4]), packh2(acc[r0][5], acc[r1][5]),
                    packh2(acc[r0][6], acc[r1][6]), packh2(acc[r0][7], acc[r1][7])};
        *(uint4*)row = pa;
        *(uint4*)(row + 64) = pb;
      }
    }
  }
}

// ---------------- cooperative main: 256 blocks (4 per batch) x 1024 threads ----------------
__global__ __launch_bounds__(1024) void k_main_c(
    const unsigned* proj2, const unsigned* fw2, const int* targets, const unsigned* w4,
    const float* bias4, const float* embb, const float* scoref, const float* comb_w,
    const float* comb_b, void* out, const int* flag, int steps, TanhC tc, int* bar1, int* bar2,
    float* Sx, float* ghxx, float* gxpx) {
  const int tid = threadIdx.x;
  const int g = blockIdx.x & 63;   // group = batch
  const int j = blockIdx.x >> 6;   // 0..3 within group
  const int lane = tid & 63, wid = tid >> 6;
  const int isb = flag[0];

  __shared__ float sh_pa[3072];
  __shared__ unsigned sh_phsc[HID];    // (ph, score) f16 pair
  __shared__ unsigned sh_alpha2[128];  // local alpha pairs
  __shared__ float sh_hidden[HID];
  __shared__ unsigned sh_h2[128];
  __shared__ float sh_red[16];

  float my_sc = (tid < HID) ? scoref[tid] : 0.f;
  if (tid < HID) sh_hidden[tid] = 0.f;
  if (tid < 128) sh_h2[tid] = 0u;
  __syncthreads();

  const v2h C0 = v2splat(tc.c[0]), C1 = v2splat(tc.c[1]), C2 = v2splat(tc.c[2]),
            C3 = v2splat(tc.c[3]), C4 = v2splat(tc.c[4]), C5 = v2splat(tc.c[5]),
            C6 = v2splat(tc.c[6]);
  const v2h CLO = v2splat(-3.9f), CHI = v2splat(3.9f);
  const v2h VS = v2splat(0.0625f);

  const unsigned* pbase = proj2 + (long)g * HID * 512 + j * 128;
  const unsigned* fwbase = fw2 + ((long)g * 512 + j * 128) * GDIM;

  for (int step = 0; step < steps; ++step) {
    const int tgt = targets[g * steps + step];
    const int par = step & 1;
    float* S_cur = Sx + par * 256;
    float* ghx_cur = ghxx + (long)par * 64 * GDIM;
    float* gxp_cur = gxpx + (long)par * 64 * 4 * GDIM;

    // ---- A: ph (all 256 cols, replicated) + gh slice j (192 cols) ----
    {
      const int chunk = tid >> 8, col = tid & 255;
      float a = 0.f;
      const unsigned* wp = w4 + (long)(chunk * 32) * 1024 + col;
#pragma unroll 8
      for (int l = 0; l < 32; ++l) a = f_dot2(u2v(sh_h2[chunk * 32 + l]), u2v(wp[l * 1024]), a);
      sh_pa[chunk * 256 + col] = a;
    }
    if (tid < 768) {
      const int ch = tid / 192, cl = tid % 192;
      const int gcol = 256 + j * 192 + cl;
      float a = 0.f;
      const unsigned* wp = w4 + (long)(ch * 32) * 1024 + gcol;
#pragma unroll 8
      for (int l = 0; l < 32; ++l) a = f_dot2(u2v(sh_h2[ch * 32 + l]), u2v(wp[l * 1024]), a);
      sh_pa[1024 + ch * 192 + cl] = a;
    }
    __syncthreads();
    if (tid < 256) {
      float ph = sh_pa[tid] + sh_pa[256 + tid] + sh_pa[512 + tid] + sh_pa[768 + tid] + bias4[tid];
      sh_phsc[tid] = packh2(ph, my_sc);
    } else if (tid < 448) {
      int cl = tid - 256;
      float gv = sh_pa[1024 + cl] + sh_pa[1024 + 192 + cl] + sh_pa[1024 + 384 + cl] +
                 sh_pa[1024 + 576 + cl] + bias4[256 + j * 192 + cl];
      ghx_cur[(long)g * GDIM + j * 192 + cl] = gv;
    }
    __syncthreads();

    // ---- B: e partials for local t range (256 t = 128 pairs) ----
    {
      const int hh = tid >> 7, tpl = tid & 127;
      const unsigned* pb = pbase + tpl;
      v2h acc = v2splat(0.f);
      float f0 = 0.f, f1 = 0.f;
#pragma unroll 8
      for (int hi = 0; hi < 32; ++hi) {
        int h = hh * 32 + hi;
        v2h ps = u2v(sh_phsc[h]);
        v2h phb = {ps.x, ps.x};
        v2h scb = {ps.y, ps.y};
        v2h x = u2v(pb[(long)h * 512]) + phb;
        x = __builtin_elementwise_max(x, CLO);
        x = __builtin_elementwise_min(x, CHI);
        v2h v = x * x * VS;
        v2h p = C6;
        p = p * v + C5;
        p = p * v + C4;
        p = p * v + C3;
        p = p * v + C2;
        p = p * v + C1;
        p = p * v + C0;
        acc = acc + scb * (p * x);
      }
      f0 = (float)acc.x;
      f1 = (float)acc.y;
      sh_pa[(hh * 128 + tpl) * 2] = f0;
      sh_pa[(hh * 128 + tpl) * 2 + 1] = f1;
    }
    __syncthreads();
    float p0 = 0.f, p1 = 0.f;
    if (tid < 128) {
      float e0 = 0.f, e1 = 0.f;
#pragma unroll
      for (int hh = 0; hh < 8; ++hh) {
        e0 += sh_pa[(hh * 128 + tid) * 2];
        e1 += sh_pa[(hh * 128 + tid) * 2 + 1];
      }
      p0 = exp2f(e0 * 1.44269504f);
      p1 = exp2f(e1 * 1.44269504f);
      float s = wave_sum64(p0 + p1);
      if (lane == 63) sh_red[wid] = s;
    }
    __syncthreads();
    if (tid == 0) S_cur[g * 4 + j] = sh_red[0] + sh_red[1];

    // ---- barrier 1 ----
    __syncthreads();
    if (tid == 0) {
      __hip_atomic_fetch_add(&bar1[g], 1, __ATOMIC_ACQ_REL, __HIP_MEMORY_SCOPE_AGENT);
      const int tgt4 = 4 * (step + 1);
      while (__hip_atomic_load(&bar1[g], __ATOMIC_RELAXED, __HIP_MEMORY_SCOPE_AGENT) < tgt4)
        __builtin_amdgcn_s_sleep(2);
      (void)__hip_atomic_load(&bar1[g], __ATOMIC_ACQUIRE, __HIP_MEMORY_SCOPE_AGENT);
    }
    __syncthreads();
    if (tid < 128) {
      float D = S_cur[g * 4] + S_cur[g * 4 + 1] + S_cur[g * 4 + 2] + S_cur[g * 4 + 3];
      float rs = 1.0f / D;
      sh_alpha2[tid] = packh2(p0 * rs, p1 * rs);
    }
    __syncthreads();

    // ---- D': gxp_j[col] = sum over local 128 pairs of fdot2(alpha2, FW2) ----
    if (tid < 768) {
      const int sub = tid / 192, cg = tid % 192;
      const int c4 = cg * 4;
      const uint4* fr = (const uint4*)(fwbase + (long)(sub * 32) * GDIM + c4);
      float a0 = 0.f, a1 = 0.f, a2 = 0.f, a3 = 0.f;
#pragma unroll 4
      for (int i = 0; i < 32; ++i) {
        v2h al = u2v(sh_alpha2[sub * 32 + i]);
        uint4 w = fr[(long)i * 192];
        a0 = f_dot2(al, u2v(w.x), a0);
        a1 = f_dot2(al, u2v(w.y), a1);
        a2 = f_dot2(al, u2v(w.z), a2);
        a3 = f_dot2(al, u2v(w.w), a3);
      }
      *(float4*)&sh_pa[sub * GDIM + c4] = make_float4(a0, a1, a2, a3);
    }
    __syncthreads();
    if (tid < 768) {
      float v = sh_pa[tid] + sh_pa[GDIM + tid] + sh_pa[2 * GDIM + tid] + sh_pa[3 * GDIM + tid];
      gxp_cur[((long)g * 4 + j) * GDIM + tid] = v;
    }

    // ---- barrier 2 ----
    __syncthreads();
    if (tid == 0) {
      __hip_atomic_fetch_add(&bar2[g], 1, __ATOMIC_ACQ_REL, __HIP_MEMORY_SCOPE_AGENT);
      const int tgt4 = 4 * (step + 1);
      while (__hip_atomic_load(&bar2[g], __ATOMIC_RELAXED, __HIP_MEMORY_SCOPE_AGENT) < tgt4)
        __builtin_amdgcn_s_sleep(2);
      (void)__hip_atomic_load(&bar2[g], __ATOMIC_ACQUIRE, __HIP_MEMORY_SCOPE_AGENT);
    }
    __syncthreads();

    // ---- G: gates -> h_new (replicated, bit-identical across blocks) ----
    if (tid < 256) {
      const float* eb = embb + (long)tgt * GDIM;
      float gr = eb[tid], gz = eb[tid + 256], gn = eb[tid + 512];
#pragma unroll
      for (int jj = 0; jj < 4; ++jj) {
        const float* gp = gxp_cur + ((long)g * 4 + jj) * GDIM;
        gr += gp[tid];
        gz += gp[tid + 256];
        gn += gp[tid + 512];
      }
      const float* gh = ghx_cur + (long)g * GDIM;
      float hr = gh[tid], hz = gh[tid + 256], hn = gh[tid + 512];
      float r = 1.f / (1.f + __expf(-(gr + hr)));
      float z = 1.f / (1.f + __expf(-(gz + hz)));
      float n = tanhf(gn + r * hn);
      sh_hidden[tid] = (1.f - z) * n + z * sh_hidden[tid];
    }
    __syncthreads();

    // ---- H: repack h2; rotating leader writes outputs ----
    if (tid < 128) sh_h2[tid] = packh2(sh_hidden[2 * tid], sh_hidden[2 * tid + 1]);
    if (j == (step & 3)) {
      float hv[4];
      if (tid < 64) {
#pragma unroll
        for (int k = 0; k < 4; ++k) hv[k] = sh_hidden[lane + 64 * k];
      }
      if (tid < 34) {
        float a = comb_b[tid];
#pragma unroll
        for (int k = 0; k < 4; ++k) {
          for (int l = 0; l < 64; ++l) {
            float h = __builtin_bit_cast(
                float, __builtin_amdgcn_readlane(__builtin_bit_cast(int, hv[k]), l));
            a += h * comb_w[(64 * k + l) * 34 + tid];
          }
        }
        long so;
        float vv;
        if (tid < 30) {
          so = ((long)g * steps + step) * 30 + tid;
          vv = a;
        } else {
          so = (long)BB * steps * 30 + ((long)g * steps + step) * 4 + (tid - 30);
          vv = 1.f / (1.f + __expf(-a));
        }
        if (isb)
          ((__hip_bfloat16*)out)[so] = __float2bfloat16(vv);
        else
          ((float*)out)[so] = vv;
      }
    }
    __syncthreads();
  }
}

// ---------------- host: tanh poly fit ----------------
static void fit_tanh(float cf[7]) {
  double A[7][7] = {{0}}, r[7] = {0};
  const int N = 1024;
  for (int i = 1; i <= N; ++i) {
    double x = 3.9 * i / N;
    double v = (x * x) / 16.0;
    double t = tanh(x);
    double phi[7];
    double pw = x;
    for (int jj = 0; jj < 7; ++jj) {
      phi[jj] = pw;
      pw *= v;
    }
    for (int jj = 0; jj < 7; ++jj) {
      r[jj] += phi[jj] * t;
      for (int k = 0; k < 7; ++k) A[jj][k] += phi[jj] * phi[k];
    }
  }
  for (int col = 0; col < 7; ++col) {
    int piv = col;
    for (int rr = col + 1; rr < 7; ++rr)
      if (fabs(A[rr][col]) > fabs(A[piv][col])) piv = rr;
    if (piv != col) {
      for (int k = 0; k < 7; ++k) {
        double tmp = A[col][k];
        A[col][k] = A[piv][k];
        A[piv][k] = tmp;
      }
      double tb = r[col];
      r[col] = r[piv];
      r[piv] = tb;
    }
    double d = A[col][col];
    for (int rr = col + 1; rr < 7; ++rr) {
      double f = A[rr][col] / d;
      for (int k = col; k < 7; ++k) A[rr][k] -= f * A[col][k];
      r[rr] -= f * r[col];
    }
  }
  double c[7];
  for (int col = 6; col >= 0; --col) {
    double ss = r[col];
    for (int k = col + 1; k < 7; ++k) ss -= A[col][k] * c[k];
    c[col] = ss / A[col][col];
  }
  for (int jj = 0; jj < 7; ++jj) cf[jj] = (float)c[jj];
}

extern "C" void kernel_launch(void* const* d_in, const int* in_sizes, int n_in, void* d_out,
                              int out_size, void* d_ws, size_t ws_size, hipStream_t stream) {
  (void)n_in;
  (void)out_size;
  (void)ws_size;
  const void* fea = d_in[0];
  const int* targets = (const int*)d_in[1];
  const void* i2h_w = d_in[2];
  const void* h2h_w = d_in[3];
  const void* h2h_b = d_in[4];
  const void* score_w = d_in[5];
  const void* gru_w_ih = d_in[6];
  const void* gru_w_hh = d_in[7];
  const void* gru_b_ih = d_in[8];
  const void* gru_b_hh = d_in[9];
  const void* sg1_w = d_in[10];
  const void* sg1_b = d_in[11];
  const void* sg2_w = d_in[12];
  const void* sg2_b = d_in[13];
  const void* lg1_w = d_in[14];
  const void* lg1_b = d_in[15];
  const void* lg2_w = d_in[16];
  const void* lg2_b = d_in[17];
  const int steps = in_sizes[1] / BB;  // 501

  char* p = (char*)d_ws;
  auto alloc = [&](size_t bytes) {
    char* r = p;
    p += (bytes + 255) & ~(size_t)255;
    return r;
  };
  unsigned* proj2 = (unsigned*)alloc((size_t)BB * HID * 512 * 4);    // 33.5 MB
  unsigned* fw2 = (unsigned*)alloc((size_t)BB * 512 * GDIM * 4);     // 100.7 MB
  unsigned* wc2 = (unsigned*)alloc((size_t)256 * 1024 * 4);          // 1 MB
  unsigned* w4 = (unsigned*)alloc((size_t)128 * 1024 * 4);           // 0.5 MB
  float* bias4 = (float*)alloc(1024 * 4);
  float* embb = (float*)alloc((size_t)NEMB * GDIM * 4);
  float* scoref = (float*)alloc(256 * 4);
  float* combw = (float*)alloc(256 * 34 * 4);
  float* combb = (float*)alloc(64 * 4);
  int* flag = (int*)alloc(256);
  int* bars = (int*)alloc(4096);  // bar1[64], bar2[64] (+pad)
  float* Sx = (float*)alloc((size_t)2 * 64 * 4 * 4);
  float* ghxx = (float*)alloc((size_t)2 * 64 * GDIM * 4);
  float* gxpx = (float*)alloc((size_t)2 * 64 * 4 * GDIM * 4);
  int* bar1 = bars;
  int* bar2 = bars + 64;

  TanhC tc;
  fit_tanh(tc.c);

  hipMemsetAsync(bars, 0, 4096, stream);
  k_sniff<<<1, 256, 0, stream>>>(fea, flag);
  k_wc<<<1024, 256, 0, stream>>>(i2h_w, gru_w_ih, wc2, flag);
  k_w4<<<512, 256, 0, stream>>>(h2h_w, gru_w_hh, w4, flag);
  k_bias4<<<4, 256, 0, stream>>>(h2h_b, gru_b_hh, bias4, flag);
  k_embb<<<90, 256, 0, stream>>>(gru_w_ih, gru_b_ih, embb, flag);
  k_cvt_f<<<1, 256, 0, stream>>>(score_w, scoref, 256, flag);
  k_comb<<<1, 256, 0, stream>>>(sg1_w, sg1_b, sg2_w, sg2_b, lg1_w, lg1_b, lg2_w, lg2_b, combw,
                                combb, flag);
  k_gemm<<<4096, 256, 0, stream>>>(fea, wc2, proj2, fw2, flag);

  k_main_c<<<256, 1024, 0, stream>>>(proj2, fw2, targets, w4, bias4, embb, scoref, combw, combb,
                                     d_out, flag, steps, tc, bar1, bar2, Sx, ghxx, gxpx);
}

// Round 6
// 21718.932 us; speedup vs baseline: 5.6567x; 1.1596x over previous
//
#include <hip/hip_runtime.h>
#include <hip/hip_bf16.h>
#include <hip/hip_fp16.h>
#include <math.h>

#define BB 64
#define CDIM 512
#define TT 1024
#define HID 256
#define NEMB 30
#define GDIM 768

typedef _Float16 v2h __attribute__((ext_vector_type(2)));

struct TanhC { float c[7]; };

__device__ inline float f_dot2(v2h a, v2h b, float c) {
  return __builtin_amdgcn_fdot2(a, b, c, false);
}
__device__ inline v2h u2v(unsigned u) { return __builtin_bit_cast(v2h, u); }
__device__ inline unsigned v2u(v2h h) { return __builtin_bit_cast(unsigned, h); }
__device__ inline unsigned packh2(float a, float b) {
  v2h t = {(_Float16)a, (_Float16)b};
  return v2u(t);
}
__device__ inline v2h v2splat(float f) {
  _Float16 h = (_Float16)f;
  v2h r = {h, h};
  return r;
}

// input loader: isb=1 -> bf16, else f32
__device__ inline float ldin(const void* p, long i, int isb) {
  if (isb) {
    unsigned u = ((const unsigned short*)p)[i];
    return __uint_as_float(u << 16);
  }
  return ((const float*)p)[i];
}

template <int CTRL, int RM, int BM, bool BC>
__device__ inline float dpp_add(float v) {
  int m = __builtin_amdgcn_update_dpp(0, __builtin_bit_cast(int, v), CTRL, RM, BM, BC);
  return v + __builtin_bit_cast(float, m);
}
__device__ inline float wave_sum64(float v) {
  v = dpp_add<0x111, 0xf, 0xf, true>(v);
  v = dpp_add<0x112, 0xf, 0xf, true>(v);
  v = dpp_add<0x114, 0xf, 0xe, false>(v);
  v = dpp_add<0x118, 0xf, 0xc, false>(v);
  v = dpp_add<0x142, 0xa, 0xf, false>(v);
  v = dpp_add<0x143, 0xc, 0xf, false>(v);
  return v;
}

// ---------------- dtype sniffer ----------------
__global__ void k_sniff(const void* fea, int* flag) {
  __shared__ int s[256];
  int tid = threadIdx.x;
  const unsigned short* u16 = (const unsigned short*)fea;
  int cnt = 0;
  for (int i = tid; i < 2048; i += 256) {
    unsigned u = u16[2 * i];
    float v = __uint_as_float(u << 16);
    float a = fabsf(v);
    if (a > 1e-6f && a < 16.0f) cnt++;
  }
  s[tid] = cnt;
  __syncthreads();
  for (int off = 128; off > 0; off >>= 1) {
    if (tid < off) s[tid] += s[tid + off];
    __syncthreads();
  }
  if (tid == 0) flag[0] = (s[0] > 1024) ? 1 : 0;
}

__global__ void k_cvt_f(const void* src, float* dst, long n, const int* flag) {
  int isb = flag[0];
  long i = (long)blockIdx.x * blockDim.x + threadIdx.x;
  long stride = (long)gridDim.x * blockDim.x;
  for (; i < n; i += stride) dst[i] = ldin(src, i, isb);
}

// Wc2[cp][col]: pair-rows of [i2h (cols 0-255) | Wih[:512] (cols 256-1023)], half2 bits
__global__ void k_wc(const void* i2h, const void* wih, unsigned* wc2, const int* flag) {
  int isb = flag[0];
  int idx = blockIdx.x * 256 + threadIdx.x;  // 1024 blocks
  int cp = idx >> 10, col = idx & 1023;
  float a, b;
  if (col < 256) {
    a = ldin(i2h, (long)(2 * cp) * 256 + col, isb);
    b = ldin(i2h, (long)(2 * cp + 1) * 256 + col, isb);
  } else {
    int j = col - 256;
    a = ldin(wih, (long)(2 * cp) * GDIM + j, isb);
    b = ldin(wih, (long)(2 * cp + 1) * GDIM + j, isb);
  }
  wc2[idx] = packh2(a, b);
}

// w4[l][col]: pair-rows of [h2h (cols 0-255) | whh (cols 256-1023)]
__global__ void k_w4(const void* h2hw, const void* whhw, unsigned* w4, const int* flag) {
  int isb = flag[0];
  int idx = blockIdx.x * 256 + threadIdx.x;  // 512 blocks
  int l = idx >> 10, col = idx & 1023;
  float a, b2;
  if (col < 256) {
    a = ldin(h2hw, (long)(2 * l) * 256 + col, isb);
    b2 = ldin(h2hw, (long)(2 * l + 1) * 256 + col, isb);
  } else {
    int j = col - 256;
    a = ldin(whhw, (long)(2 * l) * GDIM + j, isb);
    b2 = ldin(whhw, (long)(2 * l + 1) * GDIM + j, isb);
  }
  w4[idx] = packh2(a, b2);
}

__global__ void k_bias4(const void* h2hb, const void* bhh, float* bias4, const int* flag) {
  int isb = flag[0];
  int col = blockIdx.x * 256 + threadIdx.x;  // 4 blocks
  bias4[col] = (col < 256) ? ldin(h2hb, col, isb) : ldin(bhh, col - 256, isb);
}

// embb[e][col] = Wih[512+e][col] + b_ih[col]
__global__ void k_embb(const void* wih, const void* bih, float* embb, const int* flag) {
  int isb = flag[0];
  int idx = blockIdx.x * 256 + threadIdx.x;  // 90 blocks
  if (idx >= NEMB * GDIM) return;
  int e = idx / GDIM, col = idx % GDIM;
  embb[idx] = ldin(wih, (long)(512 + e) * GDIM + col, isb) + ldin(bih, col, isb);
}

// combined output head
__global__ void k_comb(const void* sg1w, const void* sg1b, const void* sg2w, const void* sg2b,
                       const void* lg1w, const void* lg1b, const void* lg2w, const void* lg2b,
                       float* comb_w, float* comb_b, const int* flag) {
  int isb = flag[0];
  int tid = threadIdx.x;
  float acc[34];
#pragma unroll
  for (int o = 0; o < 34; ++o) acc[o] = 0.f;
  for (int m = 0; m < HID; ++m) {
    float s1 = ldin(sg1w, (long)tid * HID + m, isb);
    float l1 = ldin(lg1w, (long)tid * HID + m, isb);
#pragma unroll
    for (int o = 0; o < 30; ++o) acc[o] += s1 * ldin(sg2w, (long)m * NEMB + o, isb);
#pragma unroll
    for (int o = 0; o < 4; ++o) acc[30 + o] += l1 * ldin(lg2w, (long)m * 4 + o, isb);
  }
  for (int o = 0; o < 34; ++o) comb_w[tid * 34 + o] = acc[o];
  if (tid < 34) {
    float a = 0.f;
    if (tid < 30) {
      for (int m = 0; m < HID; ++m) a += ldin(sg1b, m, isb) * ldin(sg2w, (long)m * NEMB + tid, isb);
      a += ldin(sg2b, tid, isb);
    } else {
      int o = tid - 30;
      for (int m = 0; m < HID; ++m) a += ldin(lg1b, m, isb) * ldin(lg2w, (long)m * 4 + o, isb);
      a += ldin(lg2b, o, isb);
    }
    comb_b[tid] = a;
  }
}

// ---------------- tiled GEMM: C[b][t][col] = fea[b][:,t] . Wc[:,col] ----------------
// col<256 -> pp[b][tp][col] ; col>=256 -> fw2[b][tp][col-256]   (both t-pair-major)
__global__ __launch_bounds__(256) void k_gemm(const void* fea, const unsigned* wc2,
                                              unsigned* pp, unsigned* fw2, const int* flag) {
  const int isb = flag[0];
  const int blk = blockIdx.x;
  const int b = blk >> 6;
  const int tt = (blk >> 3) & 7;
  const int cc = blk & 7;
  const int t0 = tt * 128, c0 = cc * 128;
  __shared__ __align__(16) unsigned At[32][136];
  __shared__ __align__(16) unsigned Wt[32][136];
  const int tid = threadIdx.x;
  const int cp_l = tid >> 3, sg = tid & 7;
  const int tm = tid & 15, tn = tid >> 4;
  float acc[8][8];
#pragma unroll
  for (int i = 0; i < 8; ++i)
#pragma unroll
    for (int jj = 0; jj < 8; ++jj) acc[i][jj] = 0.f;

  for (int kt = 0; kt < 8; ++kt) {
    const int crow = (kt * 32 + cp_l) * 2;
    if (isb) {
      const unsigned short* f0p =
          (const unsigned short*)fea + ((long)b * CDIM + crow) * TT + t0 + sg * 16;
      const unsigned short* f1p = f0p + TT;
#pragma unroll
      for (int q = 0; q < 2; ++q) {
        ushort4 u0a = ((const ushort4*)f0p)[2 * q];
        ushort4 u0b = ((const ushort4*)f0p)[2 * q + 1];
        ushort4 u1a = ((const ushort4*)f1p)[2 * q];
        ushort4 u1b = ((const ushort4*)f1p)[2 * q + 1];
        unsigned short a0[8] = {u0a.x, u0a.y, u0a.z, u0a.w, u0b.x, u0b.y, u0b.z, u0b.w};
        unsigned short a1[8] = {u1a.x, u1a.y, u1a.z, u1a.w, u1b.x, u1b.y, u1b.z, u1b.w};
#pragma unroll
        for (int e = 0; e < 8; ++e) {
          float f0 = __uint_as_float(((unsigned)a0[e]) << 16);
          float f1 = __uint_as_float(((unsigned)a1[e]) << 16);
          At[cp_l][sg * 16 + q * 8 + e] = packh2(f0, f1);
        }
      }
    } else {
      const float* f0p = (const float*)fea + ((long)b * CDIM + crow) * TT + t0 + sg * 16;
      const float* f1p = f0p + TT;
#pragma unroll
      for (int q = 0; q < 4; ++q) {
        float4 v0 = ((const float4*)f0p)[q];
        float4 v1 = ((const float4*)f1p)[q];
        At[cp_l][sg * 16 + q * 4 + 0] = packh2(v0.x, v1.x);
        At[cp_l][sg * 16 + q * 4 + 1] = packh2(v0.y, v1.y);
        At[cp_l][sg * 16 + q * 4 + 2] = packh2(v0.z, v1.z);
        At[cp_l][sg * 16 + q * 4 + 3] = packh2(v0.w, v1.w);
      }
    }
    {
      const uint4* wp = (const uint4*)(wc2 + (long)(kt * 32 + cp_l) * 1024 + c0 + sg * 16);
#pragma unroll
      for (int q = 0; q < 4; ++q) {
        uint4 w = wp[q];
        Wt[cp_l][sg * 16 + q * 4 + 0] = w.x;
        Wt[cp_l][sg * 16 + q * 4 + 1] = w.y;
        Wt[cp_l][sg * 16 + q * 4 + 2] = w.z;
        Wt[cp_l][sg * 16 + q * 4 + 3] = w.w;
      }
    }
    __syncthreads();
    for (int cp = 0; cp < 32; ++cp) {
      uint4 aq0 = *(const uint4*)&At[cp][tm * 4];
      uint4 aq1 = *(const uint4*)&At[cp][64 + tm * 4];
      uint4 bq0 = *(const uint4*)&Wt[cp][tn * 4];
      uint4 bq1 = *(const uint4*)&Wt[cp][64 + tn * 4];
      unsigned av[8] = {aq0.x, aq0.y, aq0.z, aq0.w, aq1.x, aq1.y, aq1.z, aq1.w};
      unsigned bv[8] = {bq0.x, bq0.y, bq0.z, bq0.w, bq1.x, bq1.y, bq1.z, bq1.w};
#pragma unroll
      for (int ti = 0; ti < 8; ++ti)
#pragma unroll
        for (int ci = 0; ci < 8; ++ci)
          acc[ti][ci] = f_dot2(u2v(av[ti]), u2v(bv[ci]), acc[ti][ci]);
    }
    __syncthreads();
  }

#pragma unroll
  for (int q = 0; q < 2; ++q) {
    const int tq = t0 + q * 64 + tm * 4;
#pragma unroll
    for (int pr = 0; pr < 2; ++pr) {
      const int tp = (tq >> 1) + pr;
      const int r0 = q * 4 + 2 * pr, r1 = r0 + 1;
      unsigned* row;
      if (cc < 2)
        row = pp + ((long)b * 512 + tp) * 256 + c0 + tn * 4;
      else
        row = fw2 + ((long)b * 512 + tp) * GDIM + (c0 - 256) + tn * 4;
      uint4 pa = {packh2(acc[r0][0], acc[r1][0]), packh2(acc[r0][1], acc[r1][1]),
                  packh2(acc[r0][2], acc[r1][2]), packh2(acc[r0][3], acc[r1][3])};
      uint4 pb = {packh2(acc[r0][4], acc[r1][4]), packh2(acc[r0][5], acc[r1][5]),
                  packh2(acc[r0][6], acc[r1][6]), packh2(acc[r0][7], acc[r1][7])};
      *(uint4*)row = pa;
      *(uint4*)(row + 64) = pb;
    }
  }
}

// ---------------- cooperative main v2: 256 blocks (4/batch) x 1024 threads, ONE barrier ----
__global__ __launch_bounds__(1024, 4) void k_main_c2(
    const unsigned* pp, const unsigned* fw2, const int* targets, const unsigned* w4,
    const float* bias4, const float* embb, const float* scoref, const float* comb_w,
    const float* comb_b, void* out, const int* flag, int steps, TanhC tc, int* bar1, float* Sx,
    float* ghxx, float* gxpx) {
  const int tid = threadIdx.x;
  const int g = blockIdx.x & 63;  // batch
  const int j = blockIdx.x >> 6;  // 0..3 within group (same XCD: stride-64 blockIdx)
  const int lane = tid & 63, wid = tid >> 6;
  const int isb = flag[0];

  __shared__ __align__(16) float sh_pa[3072];  // A partials / B eb / D' partials
  __shared__ unsigned sh_phsc[264];            // swizzled (ph,score): idx=(h>>5)*33+(h&31)
  __shared__ unsigned sh_alpha2[128];          // unnormalized p pairs (f16)
  __shared__ float sh_hidden[HID];
  __shared__ unsigned sh_h2[128];
  __shared__ float sh_red[4];

  float my_sc = (tid < HID) ? scoref[tid] : 0.f;
  if (tid < HID) sh_hidden[tid] = 0.f;
  if (tid < 128) sh_h2[tid] = 0u;
  __syncthreads();

  const v2h C0 = v2splat(tc.c[0]), C1 = v2splat(tc.c[1]), C2 = v2splat(tc.c[2]),
            C3 = v2splat(tc.c[3]), C4 = v2splat(tc.c[4]), C5 = v2splat(tc.c[5]),
            C6 = v2splat(tc.c[6]);
  const v2h CLO = v2splat(-3.9f), CHI = v2splat(3.9f);
  const v2h VS = v2splat(0.0625f);

  const unsigned* ppbase = pp + ((long)g * 512 + j * 128) * 256;
  const unsigned* fwbase = fw2 + ((long)g * 512 + j * 128) * GDIM;

  // D' mapping (fixed per thread)
  const int dsub = (tid < 768) ? tid / 192 : 0;
  const int dcg = (tid < 768) ? tid % 192 : 0;
  const uint4* frbase = (const uint4*)(fwbase + (long)(dsub * 32) * GDIM) + dcg;

  // B mapping
  const int btp = tid >> 3, bhc = tid & 7;
  const uint4* prow = (const uint4*)(ppbase + (long)btp * 256) + bhc * 8;

  for (int step = 0; step < steps; ++step) {
    const int tgt = targets[g * steps + step];
    const int par = step & 1;
    float* S_cur = Sx + par * 256;
    float* ghx_cur = ghxx + (long)par * 64 * GDIM;
    float* gxp_cur = gxpx + (long)par * 64 * 4 * GDIM;

    // ---- FW register prefetch (independent of step state; in flight under A/B/C) ----
    uint4 pf[8];
#pragma unroll
    for (int i = 0; i < 8; ++i) pf[i] = frbase[(long)i * 192];

    // ---- A: ph (256 cols, replicated) + gh slice j (192 cols) ----
    {
      const int chunk = tid >> 8, col = tid & 255;
      float a = 0.f;
      const unsigned* wp = w4 + (long)(chunk * 32) * 1024 + col;
#pragma unroll 8
      for (int l = 0; l < 32; ++l) a = f_dot2(u2v(sh_h2[chunk * 32 + l]), u2v(wp[l * 1024]), a);
      sh_pa[chunk * 256 + col] = a;
    }
    if (tid < 768) {
      const int ch = tid / 192, cl = tid % 192;
      const int gcol = 256 + j * 192 + cl;
      float a = 0.f;
      const unsigned* wp = w4 + (long)(ch * 32) * 1024 + gcol;
#pragma unroll 8
      for (int l = 0; l < 32; ++l) a = f_dot2(u2v(sh_h2[ch * 32 + l]), u2v(wp[l * 1024]), a);
      sh_pa[1024 + ch * 192 + cl] = a;
    }
    __syncthreads();
    if (tid < 256) {
      float ph = sh_pa[tid] + sh_pa[256 + tid] + sh_pa[512 + tid] + sh_pa[768 + tid] + bias4[tid];
      sh_phsc[(tid >> 5) * 33 + (tid & 31)] = packh2(ph, my_sc);
    } else if (tid < 448) {
      int cl = tid - 256;
      float gv = sh_pa[1024 + cl] + sh_pa[1024 + 192 + cl] + sh_pa[1024 + 384 + cl] +
                 sh_pa[1024 + 576 + cl] + bias4[256 + j * 192 + cl];
      ghx_cur[(long)g * GDIM + j * 192 + cl] = gv;
    }
    __syncthreads();

    // ---- B: e partials; thread = (t-pair btp, h-chunk bhc of 32) ----
    {
      v2h acc = v2splat(0.f);
#pragma unroll
      for (int q = 0; q < 8; ++q) {
        uint4 w = prow[q];
        unsigned we[4] = {w.x, w.y, w.z, w.w};
#pragma unroll
        for (int e = 0; e < 4; ++e) {
          int hl = q * 4 + e;
          v2h ps = u2v(sh_phsc[bhc * 33 + hl]);
          v2h phb = {ps.x, ps.x};
          v2h scb = {ps.y, ps.y};
          v2h x = u2v(we[e]) + phb;
          x = __builtin_elementwise_max(x, CLO);
          x = __builtin_elementwise_min(x, CHI);
          v2h v = x * x * VS;
          v2h p = C6;
          p = p * v + C5;
          p = p * v + C4;
          p = p * v + C3;
          p = p * v + C2;
          p = p * v + C1;
          p = p * v + C0;
          acc = acc + scb * (p * x);
        }
      }
      ((float2*)sh_pa)[btp * 9 + bhc] = make_float2((float)acc.x, (float)acc.y);
    }
    __syncthreads();

    // ---- C: p (unnormalized) + local S ----
    if (tid < 128) {
      float e0 = 0.f, e1 = 0.f;
#pragma unroll
      for (int k = 0; k < 8; ++k) {
        float2 v = ((const float2*)sh_pa)[tid * 9 + k];
        e0 += v.x;
        e1 += v.y;
      }
      float p0 = exp2f(e0 * 1.44269504f);
      float p1 = exp2f(e1 * 1.44269504f);
      sh_alpha2[tid] = packh2(p0, p1);
      float s = wave_sum64(p0 + p1);
      if (lane == 63) sh_red[wid] = s;
    }
    __syncthreads();
    if (tid == 0) S_cur[g * 4 + j] = sh_red[0] + sh_red[1];

    // ---- D': unnormalized gxp partials over local 128 pairs (4 sub-chunks of 32) ----
    if (tid < 768) {
      float a0 = 0.f, a1 = 0.f, a2 = 0.f, a3 = 0.f;
#pragma unroll
      for (int i = 0; i < 8; ++i) {
        v2h al = u2v(sh_alpha2[dsub * 32 + i]);
        a0 = f_dot2(al, u2v(pf[i].x), a0);
        a1 = f_dot2(al, u2v(pf[i].y), a1);
        a2 = f_dot2(al, u2v(pf[i].z), a2);
        a3 = f_dot2(al, u2v(pf[i].w), a3);
      }
#pragma unroll 8
      for (int i = 8; i < 32; ++i) {
        uint4 w = frbase[(long)i * 192];
        v2h al = u2v(sh_alpha2[dsub * 32 + i]);
        a0 = f_dot2(al, u2v(w.x), a0);
        a1 = f_dot2(al, u2v(w.y), a1);
        a2 = f_dot2(al, u2v(w.z), a2);
        a3 = f_dot2(al, u2v(w.w), a3);
      }
      *(float4*)&sh_pa[dsub * GDIM + dcg * 4] = make_float4(a0, a1, a2, a3);
    }
    __syncthreads();
    // reduce the 4 sub-chunks -> global exchange buffer
    if (tid < 768) {
      float v = sh_pa[tid] + sh_pa[GDIM + tid] + sh_pa[2 * GDIM + tid] + sh_pa[3 * GDIM + tid];
      gxp_cur[((long)g * 4 + j) * GDIM + tid] = v;
    }

    // ---- single barrier ----
    __syncthreads();
    if (tid == 0) {
      __hip_atomic_fetch_add(&bar1[g], 1, __ATOMIC_ACQ_REL, __HIP_MEMORY_SCOPE_AGENT);
      const int tgt4 = 4 * (step + 1);
      while (__hip_atomic_load(&bar1[g], __ATOMIC_RELAXED, __HIP_MEMORY_SCOPE_AGENT) < tgt4)
        __builtin_amdgcn_s_sleep(2);
      (void)__hip_atomic_load(&bar1[g], __ATOMIC_ACQUIRE, __HIP_MEMORY_SCOPE_AGENT);
    }
    __syncthreads();

    // ---- G: gates -> h_new (replicated, bit-identical) ----
    if (tid < 256) {
      float D = S_cur[g * 4] + S_cur[g * 4 + 1] + S_cur[g * 4 + 2] + S_cur[g * 4 + 3];
      float rs = 1.0f / D;
      const float* eb = embb + (long)tgt * GDIM;
      float gr = 0.f, gz = 0.f, gn = 0.f;
#pragma unroll
      for (int jj = 0; jj < 4; ++jj) {
        const float* gp = gxp_cur + ((long)g * 4 + jj) * GDIM;
        gr += gp[tid];
        gz += gp[tid + 256];
        gn += gp[tid + 512];
      }
      gr = gr * rs + eb[tid];
      gz = gz * rs + eb[tid + 256];
      gn = gn * rs + eb[tid + 512];
      const float* gh = ghx_cur + (long)g * GDIM;
      float hr = gh[tid], hz = gh[tid + 256], hn = gh[tid + 512];
      float r = 1.f / (1.f + __expf(-(gr + hr)));
      float z = 1.f / (1.f + __expf(-(gz + hz)));
      float n = tanhf(gn + r * hn);
      sh_hidden[tid] = (1.f - z) * n + z * sh_hidden[tid];
    }
    __syncthreads();

    // ---- H: repack h2; rotating leader writes outputs ----
    if (tid < 128) sh_h2[tid] = packh2(sh_hidden[2 * tid], sh_hidden[2 * tid + 1]);
    if (j == (step & 3)) {
      float hv[4];
      if (tid < 64) {
#pragma unroll
        for (int k = 0; k < 4; ++k) hv[k] = sh_hidden[lane + 64 * k];
      }
      if (tid < 34) {
        float a = comb_b[tid];
#pragma unroll
        for (int k = 0; k < 4; ++k) {
          for (int l = 0; l < 64; ++l) {
            float h = __builtin_bit_cast(
                float, __builtin_amdgcn_readlane(__builtin_bit_cast(int, hv[k]), l));
            a += h * comb_w[(64 * k + l) * 34 + tid];
          }
        }
        long so;
        float vv;
        if (tid < 30) {
          so = ((long)g * steps + step) * 30 + tid;
          vv = a;
        } else {
          so = (long)BB * steps * 30 + ((long)g * steps + step) * 4 + (tid - 30);
          vv = 1.f / (1.f + __expf(-a));
        }
        if (isb)
          ((__hip_bfloat16*)out)[so] = __float2bfloat16(vv);
        else
          ((float*)out)[so] = vv;
      }
    }
    __syncthreads();
  }
}

// ---------------- host: tanh poly fit ----------------
static void fit_tanh(float cf[7]) {
  double A[7][7] = {{0}}, r[7] = {0};
  const int N = 1024;
  for (int i = 1; i <= N; ++i) {
    double x = 3.9 * i / N;
    double v = (x * x) / 16.0;
    double t = tanh(x);
    double phi[7];
    double pw = x;
    for (int jj = 0; jj < 7; ++jj) {
      phi[jj] = pw;
      pw *= v;
    }
    for (int jj = 0; jj < 7; ++jj) {
      r[jj] += phi[jj] * t;
      for (int k = 0; k < 7; ++k) A[jj][k] += phi[jj] * phi[k];
    }
  }
  for (int col = 0; col < 7; ++col) {
    int piv = col;
    for (int rr = col + 1; rr < 7; ++rr)
      if (fabs(A[rr][col]) > fabs(A[piv][col])) piv = rr;
    if (piv != col) {
      for (int k = 0; k < 7; ++k) {
        double tmp = A[col][k];
        A[col][k] = A[piv][k];
        A[piv][k] = tmp;
      }
      double tb = r[col];
      r[col] = r[piv];
      r[piv] = tb;
    }
    double d = A[col][col];
    for (int rr = col + 1; rr < 7; ++rr) {
      double f = A[rr][col] / d;
      for (int k = col; k < 7; ++k) A[rr][k] -= f * A[col][k];
      r[rr] -= f * r[col];
    }
  }
  double c[7];
  for (int col = 6; col >= 0; --col) {
    double ss = r[col];
    for (int k = col + 1; k < 7; ++k) ss -= A[col][k] * c[k];
    c[col] = ss / A[col][col];
  }
  for (int jj = 0; jj < 7; ++jj) cf[jj] = (float)c[jj];
}

extern "C" void kernel_launch(void* const* d_in, const int* in_sizes, int n_in, void* d_out,
                              int out_size, void* d_ws, size_t ws_size, hipStream_t stream) {
  (void)n_in;
  (void)out_size;
  (void)ws_size;
  const void* fea = d_in[0];
  const int* targets = (const int*)d_in[1];
  const void* i2h_w = d_in[2];
  const void* h2h_w = d_in[3];
  const void* h2h_b = d_in[4];
  const void* score_w = d_in[5];
  const void* gru_w_ih = d_in[6];
  const void* gru_w_hh = d_in[7];
  const void* gru_b_ih = d_in[8];
  const void* gru_b_hh = d_in[9];
  const void* sg1_w = d_in[10];
  const void* sg1_b = d_in[11];
  const void* sg2_w = d_in[12];
  const void* sg2_b = d_in[13];
  const void* lg1_w = d_in[14];
  const void* lg1_b = d_in[15];
  const void* lg2_w = d_in[16];
  const void* lg2_b = d_in[17];
  const int steps = in_sizes[1] / BB;  // 501

  char* p = (char*)d_ws;
  auto alloc = [&](size_t bytes) {
    char* r = p;
    p += (bytes + 255) & ~(size_t)255;
    return r;
  };
  unsigned* pp = (unsigned*)alloc((size_t)BB * 512 * 256 * 4);     // 33.5 MB (t-pair-major proj)
  unsigned* fw2 = (unsigned*)alloc((size_t)BB * 512 * GDIM * 4);   // 100.7 MB
  unsigned* wc2 = (unsigned*)alloc((size_t)256 * 1024 * 4);        // 1 MB
  unsigned* w4 = (unsigned*)alloc((size_t)128 * 1024 * 4);         // 0.5 MB
  float* bias4 = (float*)alloc(1024 * 4);
  float* embb = (float*)alloc((size_t)NEMB * GDIM * 4);
  float* scoref = (float*)alloc(256 * 4);
  float* combw = (float*)alloc(256 * 34 * 4);
  float* combb = (float*)alloc(64 * 4);
  int* flag = (int*)alloc(256);
  int* bars = (int*)alloc(4096);
  float* Sx = (float*)alloc((size_t)2 * 64 * 4 * 4);
  float* ghxx = (float*)alloc((size_t)2 * 64 * GDIM * 4);
  float* gxpx = (float*)alloc((size_t)2 * 64 * 4 * GDIM * 4);
  int* bar1 = bars;

  TanhC tc;
  fit_tanh(tc.c);

  hipMemsetAsync(bars, 0, 4096, stream);
  k_sniff<<<1, 256, 0, stream>>>(fea, flag);
  k_wc<<<1024, 256, 0, stream>>>(i2h_w, gru_w_ih, wc2, flag);
  k_w4<<<512, 256, 0, stream>>>(h2h_w, gru_w_hh, w4, flag);
  k_bias4<<<4, 256, 0, stream>>>(h2h_b, gru_b_hh, bias4, flag);
  k_embb<<<90, 256, 0, stream>>>(gru_w_ih, gru_b_ih, embb, flag);
  k_cvt_f<<<1, 256, 0, stream>>>(score_w, scoref, 256, flag);
  k_comb<<<1, 256, 0, stream>>>(sg1_w, sg1_b, sg2_w, sg2_b, lg1_w, lg1_b, lg2_w, lg2_b, combw,
                                combb, flag);
  k_gemm<<<4096, 256, 0, stream>>>(fea, wc2, pp, fw2, flag);

  k_main_c2<<<256, 1024, 0, stream>>>(pp, fw2, targets, w4, bias4, embb, scoref, combw, combb,
                                      d_out, flag, steps, tc, bar1, Sx, ghxx, gxpx);
}